// Round 9
// baseline (181.057 us; speedup 1.0000x reference)
//
#include <hip/hip_runtime.h>

#define NV 2708
#define INC 1433
#define XCOLS 1472        // padded X/W cols (23*64)
#define UDIM 2752         // padded U dims (43*64)
#define PSTR 2728         // pbuf stride in shorts
#define BSTR 2752
#define SLAB ((size_t)(2752*64))   // fp32 partial slab
#define MWPR 88
#define NSP 4             // proj split-K chunks (K-chunk 384; last 320)
#define NSU 11            // gemmU split-K chunks (2752 = 10*256 + 192)

typedef __attribute__((ext_vector_type(8))) short bf16x8;
typedef __attribute__((ext_vector_type(4))) float f32x4;
typedef __attribute__((ext_vector_type(4))) unsigned short u16x4;

__device__ __forceinline__ unsigned short f2bf(float f){
  union { float f; unsigned int i; } v; v.f = f;
  return (unsigned short)((v.i + 0x7fffu + ((v.i >> 16) & 1u)) >> 16);  // RNE
}

// convert one fp32 row (INC elems, 4B-aligned base) to bf16 with zero pad to
// XCOLS. float2 via parity shift: src+sh is 8B-aligned (sh in {0,1}).
__device__ __forceinline__ void conv_row(const float* __restrict__ src,
                                         unsigned short* __restrict__ dst, int tid){
  const int sh = ((unsigned int)((size_t)src >> 2)) & 1;
  if (tid == 0){ int ce = sh ? 0 : (INC - 1); dst[ce] = f2bf(src[ce]); }
  const float2* s2 = (const float2*)(src + sh);
  for (int c2 = tid; c2 < (INC - 1)/2; c2 += 256){   // 716 pairs
    float2 v = s2[c2];
    int c = sh + c2*2;
    dst[c]     = f2bf(v.x);
    dst[c + 1] = f2bf(v.y);
  }
  for (int c = INC + tid; c < XCOLS; c += 256) dst[c] = 0;
}

// ====== convert_all: X/W/A one-row blocks + U 64x64 tiles (Ubf AND UTbf) ====
__global__ __launch_bounds__(256) void convert_all(
    const float* __restrict__ X, const float* __restrict__ WK,
    const float* __restrict__ WQ, const float* __restrict__ WV,
    const float* __restrict__ U, const int* __restrict__ A,
    unsigned short* __restrict__ Xbf, unsigned short* __restrict__ Wbf,
    unsigned short* __restrict__ Ubf, unsigned short* __restrict__ UTbf,
    unsigned int* __restrict__ Abits)
{
  __shared__ __align__(16) float tpose[64][68];   // 17.4 KB (U-tile branch)
  const int bx = blockIdx.x;
  const int tid = threadIdx.x;
  if (bx < 2752){                      // X row (float2 parity trick)
    const int row = bx;
    unsigned short* dst = Xbf + (size_t)row*XCOLS;
    if (row < NV){
      conv_row(X + (size_t)row*INC, dst, tid);
    } else {
      u16x4 zz = {0,0,0,0};
      for (int c4 = tid; c4 < XCOLS/4; c4 += 256) *(u16x4*)(dst + c4*4) = zz;
    }
  } else if (bx < 2944){               // W row (192 rows)
    const int row = bx - 2752;
    const float* s = (row < 64) ? WK : (row < 128) ? WQ : WV;
    conv_row(s + (size_t)(row & 63)*INC, Wbf + (size_t)row*XCOLS, tid);
  } else if (bx < 5652){               // A row -> bitmask (int4, grouped layout)
    const int i = bx - 2944;
    const int lane = tid & 63, wave = tid >> 6;
    const int* arow = A + (size_t)i*NV;
    unsigned int* drow = Abits + (size_t)i*MWPR;
    for (int g = wave; g < 11; g += 4){
      int base = g*256 + lane*4;
      int4 v = make_int4(0,0,0,0);
      if (base < NV) v = *(const int4*)(arow + base);
      unsigned long long m0 = __ballot(v.x != 0);
      unsigned long long m1 = __ballot(v.y != 0);
      unsigned long long m2 = __ballot(v.z != 0);
      unsigned long long m3 = __ballot(v.w != 0);
      if (lane < 8){
        unsigned long long mm = (lane < 2) ? m0 : (lane < 4) ? m1 : (lane < 6) ? m2 : m3;
        drow[g*8 + lane] = (lane & 1) ? (unsigned int)(mm >> 32) : (unsigned int)mm;
      }
    }
  } else {                             // U 64x64 tile -> Ubf rows + UTbf rows
    const int t = bx - 5652;           // < 1849
    const int tx = t % 43, ty = t / 43;
    const int r0 = ty*64, c0 = tx*64;
    #pragma unroll
    for (int j = 0; j < 4; j++){
      int row = j*16 + (tid >> 4);     // U row within tile
      int c4  = (tid & 15)*4;          // U col within tile
      float4 v = make_float4(0.f,0.f,0.f,0.f);
      if (r0 + row < NV && c0 + c4 < NV)        // NV%4==0: float4 fully valid
        v = *(const float4*)(U + (size_t)(r0+row)*NV + c0 + c4);
      *(float4*)&tpose[row][c4] = v;
      u16x4 h = { f2bf(v.x), f2bf(v.y), f2bf(v.z), f2bf(v.w) };
      *(u16x4*)(Ubf + (size_t)(r0+row)*UDIM + c0 + c4) = h;
    }
    __syncthreads();
    const int i = tid >> 2;            // UT row within tile (UT row c0+i)
    #pragma unroll
    for (int j = 0; j < 4; j++){
      int kk = ((tid & 3) + j*4)*4;    // UT col (k) start
      u16x4 h = { f2bf(tpose[kk+0][i]), f2bf(tpose[kk+1][i]),
                  f2bf(tpose[kk+2][i]), f2bf(tpose[kk+3][i]) };
      *(u16x4*)(UTbf + (size_t)(c0+i)*UDIM + r0 + kk) = h;
    }
  }
}

// ===== proj: partials of {K,Q,V} = Xbf @ Wbf^T. grid (86,4,3). ==============
// 32-row m-tiles, LDS-staged A+B, K-chunk 384. 1032 blocks.
// K (z=0) / V (z=2) partials in [m][c] slabs 0-3 / 8-11;
// Q (z=1) partials TRANSPOSED [c][m] in slabs 4-7 (k-contiguous for gemmG).
__global__ __launch_bounds__(256) void proj(
    const unsigned short* __restrict__ Xbf, const unsigned short* __restrict__ Wbf,
    float* __restrict__ part)
{
  __shared__ __align__(16) unsigned short At[32*72];
  __shared__ __align__(16) unsigned short Bt[64*72];
  const int tid = threadIdx.x;
  const int lane = tid & 63, wave = tid >> 6, quad = lane >> 4, lr = lane & 15;
  const int m0 = blockIdx.x * 32;
  const int s  = blockIdx.y, z = blockIdx.z;
  const int kbeg = s * 384, kend = min(kbeg + 384, XCOLS);  // last chunk 320
  const int wm = (wave & 1) * 16, wn = (wave >> 1) * 32;
  const unsigned short* Wz = Wbf + (size_t)z*64*XCOLS;
  const int arow = tid >> 3, aseg = tid & 7;
  const int brow = tid >> 2, bseg = tid & 3;
  f32x4 acc[2] = {};

  for (int k0 = kbeg; k0 < kend; k0 += 64){
    *(bf16x8*)&At[arow*72 + aseg*8] =
        *(const bf16x8*)(Xbf + (size_t)(m0+arow)*XCOLS + k0 + aseg*8);
    {
      const unsigned short* b = Wz + (size_t)brow*XCOLS + k0 + bseg*16;
      *(bf16x8*)&Bt[brow*72 + bseg*16]     = *(const bf16x8*)(b);
      *(bf16x8*)&Bt[brow*72 + bseg*16 + 8] = *(const bf16x8*)(b + 8);
    }
    __syncthreads();
    #pragma unroll
    for (int ks = 0; ks < 2; ks++){
      bf16x8 af = *(const bf16x8*)&At[(wm + lr)*72 + ks*32 + quad*8];
      bf16x8 bv[2];
      #pragma unroll
      for (int t = 0; t < 2; t++)
        bv[t] = *(const bf16x8*)&Bt[(wn + t*16 + lr)*72 + ks*32 + quad*8];
      #pragma unroll
      for (int t = 0; t < 2; t++)
        acc[t] = __builtin_amdgcn_mfma_f32_16x16x32_bf16(af, bv[t], acc[t], 0, 0, 0);
    }
    __syncthreads();
  }
  if (z == 1){
    float* dstq = part + (size_t)(NSP + s) * SLAB;   // [c][m], 16B-aligned f32x4
    #pragma unroll
    for (int t = 0; t < 2; t++)
      *(f32x4*)&dstq[(size_t)(wn + t*16 + lr)*BSTR + m0 + wm + quad*4] = acc[t];
  } else {
    float* dst = part + (size_t)(z*NSP + s) * SLAB;  // z in {0,2}
    #pragma unroll
    for (int t = 0; t < 2; t++)
      #pragma unroll
      for (int e = 0; e < 4; e++)
        dst[(size_t)(m0 + wm + quad*4 + e)*64 + wn + t*16 + lr] = acc[t][e];
  }
}

// ===== gemmG: G-partials = UTbf @ Q. grid (86, 11). Folds reduce_proj. ======
// Prologue: sums K/V partial slabs -> K16f/VTf (consumed by fused_attn,
// 2 launches later; stream order = visibility). B-stage: inline-sums the 4
// transposed Q-partial slabs (same s-order as old reduce_proj -> bit-identical
// bf16) into LDS. Main loop/output identical to gemmU.
__global__ __launch_bounds__(256) void gemmG(
    const unsigned short* __restrict__ UTbf, const float* __restrict__ part,
    unsigned short* __restrict__ K16f, unsigned short* __restrict__ VTf,
    float* __restrict__ partG)
{
  __shared__ __align__(16) unsigned short At[32*72];
  __shared__ __align__(16) unsigned short Bt[64*72];
  const int tid = threadIdx.x;
  const int lane = tid & 63, wave = tid >> 6, quad = lane >> 4, lr = lane & 15;
  const int m0 = blockIdx.x * 32;
  const int s  = blockIdx.y;
  const int kbeg = s * 256, kend = min(kbeg + 256, UDIM);   // last chunk 192
  const int wm = (wave & 1) * 16, wn = (wave >> 1) * 32;
  const int arow = tid >> 3, aseg = tid & 7;
  const int bc = tid >> 2, bseg = tid & 3;
  f32x4 acc[2] = {};

  // ---- prologue: fold K/V partials (4 slabs each) into final bf16 layouts
  {
    int bid = blockIdx.y*86 + blockIdx.x;
    for (int i = bid*256 + tid; i < 2*176128; i += 946*256){
      int isV = (i >= 176128) ? 1 : 0;
      int idx = i - isV*176128;
      const float* base = part + (size_t)(isV ? 2*NSP : 0)*SLAB + idx;
      float v = ((base[0] + base[SLAB]) + base[2*SLAB]) + base[3*SLAB];
      int m = idx >> 6, c = idx & 63;
      if (m < 2720){
        unsigned short h = (m < NV) ? f2bf(v) : (unsigned short)0;
        if (!isV) K16f[((m>>4)*2 + (c>>5))*512 + (m&15)*32 + (c&31)] = h;
        else      VTf[(m>>5)*2048 + c*32 + (m&31)] = h;
      }
    }
  }

  const float* qbase = part + (size_t)NSP*SLAB;   // Q slabs 4-7, [c][m]
  for (int k0 = kbeg; k0 < kend; k0 += 64){
    *(bf16x8*)&At[arow*72 + aseg*8] =
        *(const bf16x8*)(UTbf + (size_t)(m0+arow)*UDIM + k0 + aseg*8);
    {
      const float* q = qbase + (size_t)bc*BSTR + k0 + bseg*16;
      f32x4 v0 = *(const f32x4*)(q);
      f32x4 v1 = *(const f32x4*)(q + 4);
      f32x4 v2 = *(const f32x4*)(q + 8);
      f32x4 v3 = *(const f32x4*)(q + 12);
      #pragma unroll
      for (int sl = 1; sl < NSP; sl++){
        const float* qs = q + (size_t)sl*SLAB;
        v0 += *(const f32x4*)(qs);
        v1 += *(const f32x4*)(qs + 4);
        v2 += *(const f32x4*)(qs + 8);
        v3 += *(const f32x4*)(qs + 12);
      }
      u16x4 h0 = { f2bf(v0[0]), f2bf(v0[1]), f2bf(v0[2]), f2bf(v0[3]) };
      u16x4 h1 = { f2bf(v1[0]), f2bf(v1[1]), f2bf(v1[2]), f2bf(v1[3]) };
      u16x4 h2 = { f2bf(v2[0]), f2bf(v2[1]), f2bf(v2[2]), f2bf(v2[3]) };
      u16x4 h3 = { f2bf(v3[0]), f2bf(v3[1]), f2bf(v3[2]), f2bf(v3[3]) };
      *(u16x4*)&Bt[bc*72 + bseg*16]      = h0;
      *(u16x4*)&Bt[bc*72 + bseg*16 + 4]  = h1;
      *(u16x4*)&Bt[bc*72 + bseg*16 + 8]  = h2;
      *(u16x4*)&Bt[bc*72 + bseg*16 + 12] = h3;
    }
    __syncthreads();
    #pragma unroll
    for (int ks = 0; ks < 2; ks++){
      bf16x8 af = *(const bf16x8*)&At[(wm + lr)*72 + ks*32 + quad*8];
      bf16x8 bv[2];
      #pragma unroll
      for (int t = 0; t < 2; t++)
        bv[t] = *(const bf16x8*)&Bt[(wn + t*16 + lr)*72 + ks*32 + quad*8];
      #pragma unroll
      for (int t = 0; t < 2; t++)
        acc[t] = __builtin_amdgcn_mfma_f32_16x16x32_bf16(af, bv[t], acc[t], 0, 0, 0);
    }
    __syncthreads();
  }
  float* dst = partG + (size_t)s * SLAB;
  #pragma unroll
  for (int t = 0; t < 2; t++)
    #pragma unroll
    for (int e = 0; e < 4; e++)
      dst[(size_t)(m0 + wm + quad*4 + e)*64 + wn + t*16 + lr] = acc[t][e];
}

// ===== gemmU: partials of Arow @ Bcm^T. grid (86, 11). (F = Ubf @ G2) =======
__global__ __launch_bounds__(256) void gemmU(
    const unsigned short* __restrict__ Arow, const unsigned short* __restrict__ Bcm,
    float* __restrict__ part)
{
  __shared__ __align__(16) unsigned short At[32*72];
  __shared__ __align__(16) unsigned short Bt[64*72];
  const int tid = threadIdx.x;
  const int lane = tid & 63, wave = tid >> 6, quad = lane >> 4, lr = lane & 15;
  const int m0 = blockIdx.x * 32;
  const int s  = blockIdx.y;
  const int kbeg = s * 256, kend = min(kbeg + 256, UDIM);   // last chunk 192
  const int wm = (wave & 1) * 16, wn = (wave >> 1) * 32;
  const int arow = tid >> 3, aseg = tid & 7;
  const int bc = tid >> 2, bseg = tid & 3;
  f32x4 acc[2] = {};

  for (int k0 = kbeg; k0 < kend; k0 += 64){
    *(bf16x8*)&At[arow*72 + aseg*8] =
        *(const bf16x8*)(Arow + (size_t)(m0+arow)*UDIM + k0 + aseg*8);
    {
      const unsigned short* b = Bcm + (size_t)bc*BSTR + k0 + bseg*16;
      *(bf16x8*)&Bt[bc*72 + bseg*16]     = *(const bf16x8*)(b);
      *(bf16x8*)&Bt[bc*72 + bseg*16 + 8] = *(const bf16x8*)(b + 8);
    }
    __syncthreads();
    #pragma unroll
    for (int ks = 0; ks < 2; ks++){
      bf16x8 af = *(const bf16x8*)&At[(wm + lr)*72 + ks*32 + quad*8];
      bf16x8 bv[2];
      #pragma unroll
      for (int t = 0; t < 2; t++)
        bv[t] = *(const bf16x8*)&Bt[(wn + t*16 + lr)*72 + ks*32 + quad*8];
      #pragma unroll
      for (int t = 0; t < 2; t++)
        acc[t] = __builtin_amdgcn_mfma_f32_16x16x32_bf16(af, bv[t], acc[t], 0, 0, 0);
    }
    __syncthreads();
  }
  float* dst = part + (size_t)s * SLAB;
  #pragma unroll
  for (int t = 0; t < 2; t++)
    #pragma unroll
    for (int e = 0; e < 4; e++)
      dst[(size_t)(m0 + wm + quad*4 + e)*64 + wn + t*16 + lr] = acc[t][e];
}

// G2T16[c][m] = bf16(G[m][c] * lmbd[m]/64), zero pads. grid 688.
__global__ __launch_bounds__(256) void reduce_g(
    const float* __restrict__ partG, const float* __restrict__ lm,
    unsigned short* __restrict__ G2T)
{
  int idx = blockIdx.x*256 + threadIdx.x;
  int m = idx >> 6, c = idx & 63;
  const float* base = partG + idx;
  float v = 0.f;
  #pragma unroll
  for (int s = 0; s < NSU; s++) v += base[s*SLAB];
  unsigned short h = 0;
  if (m < NV) h = f2bf(v * lm[m] * (1.0f/64.0f));
  G2T[(size_t)c*BSTR + m] = h;
}

// ====== fused: reduce-F + |F K^T| -> masked exp + row-sum -> P V ============
// 16 rows/block, 512 threads (8 waves), 170 blocks (1 block/CU, no tail).
__global__ __launch_bounds__(512) void fused_attn(
    const float* __restrict__ partF, const unsigned short* __restrict__ K16f,
    const unsigned int* __restrict__ Abits, const unsigned short* __restrict__ VTf,
    float* __restrict__ Hout)
{
  __shared__ __align__(16) unsigned short pbuf[16*PSTR];   // 87.3 KB
  __shared__ __align__(16) unsigned short fbuf[16*64];     // 2 KB
  __shared__ unsigned int mrow[16*MWPR];                   // 5.6 KB
  __shared__ float swave[8][16];
  __shared__ float rinv[16];
  __shared__ __align__(16) float obuf[4][256];             // 4 KB
  const int tid  = threadIdx.x;
  const int lane = tid & 63, wave = tid >> 6;
  const int quad = lane >> 4, lr = lane & 15;
  const int i0 = blockIdx.x * 16;

  // stage F rows (sum 11 slabs; rows >= NV are zero in part)
  #pragma unroll
  for (int h = 0; h < 2; h++){
    int idx = h*512 + tid;              // < 1024
    const float* base = partF + (size_t)(i0 + (idx >> 6))*64 + (idx & 63);
    float v = 0.f;
    #pragma unroll
    for (int s = 0; s < NSU; s++) v += base[s*SLAB];
    fbuf[idx] = f2bf(v);
  }
  for (int idx = tid; idx < 16*MWPR; idx += 512){
    int r = idx / MWPR;
    unsigned int v = 0;
    if (i0 + r < NV) v = Abits[(size_t)(i0 + r)*MWPR + (idx - r*MWPR)];
    mrow[idx] = v;
  }
  __syncthreads();

  const bf16x8 af0 = *(const bf16x8*)&fbuf[lr*64 + quad*8];
  const bf16x8 af1 = *(const bf16x8*)&fbuf[lr*64 + 32 + quad*8];
  float psum[4] = {0.f, 0.f, 0.f, 0.f};
  {
    int t = wave;
    const unsigned short* kb = K16f + t*1024 + lr*32 + quad*8;
    bf16x8 b0 = *(const bf16x8*)(kb);
    bf16x8 b1 = *(const bf16x8*)(kb + 512);
    while (t < 170){
      int tn = t + 8;
      bf16x8 n0 = b0, n1 = b1;
      if (tn < 170){
        const unsigned short* nb = K16f + tn*1024 + lr*32 + quad*8;
        n0 = *(const bf16x8*)(nb);
        n1 = *(const bf16x8*)(nb + 512);
      }
      f32x4 sv0 = {}, sv1 = {};
      sv0 = __builtin_amdgcn_mfma_f32_16x16x32_bf16(af0, b0, sv0, 0, 0, 0);
      sv1 = __builtin_amdgcn_mfma_f32_16x16x32_bf16(af1, b1, sv1, 0, 0, 0);
      f32x4 sv = sv0 + sv1;
      {
        int col = t*16 + lr;
        int ss = col & 255, ll = ss >> 2;
        int wsh = (col >> 8)*8 + (ss & 3)*2 + (ll >> 5);
        int bit = ll & 31;
        #pragma unroll
        for (int e = 0; e < 4; e++){
          int r = quad*4 + e;
          float p = 0.f;
          if ((mrow[r*MWPR + wsh] >> bit) & 1u) p = __expf(fabsf(sv[e]));
          psum[e] += p;
          pbuf[r*PSTR + col] = f2bf(p);
        }
      }
      b0 = n0; b1 = n1; t = tn;
    }
  }
  #pragma unroll
  for (int e = 0; e < 4; e++){
    float v = psum[e];
    #pragma unroll
    for (int o = 1; o <= 8; o <<= 1) v += __shfl_xor(v, o, 64);
    if (lr == 0) swave[wave][quad*4 + e] = v;
  }
  __syncthreads();
  if (tid < 16){
    float s = 0.f;
    #pragma unroll
    for (int w = 0; w < 8; w++) s += swave[w][tid];
    rinv[tid] = (s > 0.f) ? (1.f/s) : 0.f;
  }
  __syncthreads();

  const int c0 = (wave & 3) * 16;
  const int ktbeg = (wave >> 2) ? 43 : 0;
  const int ktend = (wave >> 2) ? 85 : 43;
  f32x4 acc = {};
  {
    bf16x8 bv = *(const bf16x8*)&VTf[ktbeg*2048 + (c0 + lr)*32 + quad*8];
    for (int kt = ktbeg; kt < ktend; kt++){
      bf16x8 bn = bv;
      if (kt + 1 < ktend) bn = *(const bf16x8*)&VTf[(kt+1)*2048 + (c0 + lr)*32 + quad*8];
      bf16x8 af = *(const bf16x8*)&pbuf[lr*PSTR + kt*32 + quad*8];
      acc = __builtin_amdgcn_mfma_f32_16x16x32_bf16(af, bv, acc, 0, 0, 0);
      bv = bn;
    }
  }
  if (wave >= 4) *(f32x4*)&obuf[wave & 3][lane*4] = acc;
  __syncthreads();
  if (wave < 4){
    f32x4 o = *(const f32x4*)&obuf[wave][lane*4];
    acc += o;
    #pragma unroll
    for (int e = 0; e < 4; e++){
      int r = quad*4 + e;
      int i = i0 + r;
      if (i < NV) Hout[(size_t)i*64 + c0 + lr] = acc[e] * rinv[r];
    }
  }
}

extern "C" void kernel_launch(void* const* d_in, const int* in_sizes, int n_in,
                              void* d_out, int out_size, void* d_ws, size_t ws_size,
                              hipStream_t stream){
  (void)in_sizes; (void)n_in; (void)out_size; (void)ws_size;
  const float* X  = (const float*)d_in[0];
  const int*   A  = (const int*)d_in[1];
  const float* U  = (const float*)d_in[2];
  const float* WK = (const float*)d_in[3];
  const float* WQ = (const float*)d_in[4];
  const float* WV = (const float*)d_in[5];
  const float* lm = (const float*)d_in[6];

  char* ws = (char*)d_ws;
  size_t off = 0;
  auto alloc = [&](size_t bytes){ size_t o = off; off = (off + bytes + 255) & ~(size_t)255; return o; };
  float*          part = (float*)(ws + alloc(24*SLAB*4));                      // 16.9 MB (0-11 KQV, 12-22 G, 0-10 reused for F)
  unsigned short* Ubf  = (unsigned short*)(ws + alloc((size_t)UDIM*UDIM*2));   // 15.15 MB
  unsigned short* UTbf = (unsigned short*)(ws + alloc((size_t)UDIM*UDIM*2));   // 15.15 MB
  unsigned short* Xbf  = (unsigned short*)(ws + alloc((size_t)UDIM*XCOLS*2));  // 8.10 MB
  unsigned short* Wbf  = (unsigned short*)(ws + alloc((size_t)192*XCOLS*2));
  unsigned short* K16f = (unsigned short*)(ws + alloc((size_t)170*1024*2));
  unsigned short* G2T  = (unsigned short*)(ws + alloc((size_t)64*BSTR*2));
  unsigned short* VTf  = (unsigned short*)(ws + alloc((size_t)85*2048*2));
  unsigned int*   Abits= (unsigned int*)(ws + alloc((size_t)NV*MWPR*4));
  // total ~60 MB
  float* partG = part + (size_t)12*SLAB;

  convert_all<<<dim3(7501), 256, 0, stream>>>(X, WK, WQ, WV, U, A,
                                              Xbf, Wbf, Ubf, UTbf, Abits);
  proj<<<dim3(86, NSP, 3), 256, 0, stream>>>(Xbf, Wbf, part);
  gemmG<<<dim3(86, NSU), 256, 0, stream>>>(UTbf, part, K16f, VTf, partG);
  reduce_g<<<dim3(688), 256, 0, stream>>>(partG, lm, G2T);
  gemmU<<<dim3(86, NSU), 256, 0, stream>>>(Ubf, G2T, part);       // F partials
  fused_attn<<<dim3(170), 512, 0, stream>>>(part, K16f, Abits, VTf, (float*)d_out);
}

// Round 10
// 179.857 us; speedup vs baseline: 1.0067x; 1.0067x over previous
//
#include <hip/hip_runtime.h>

#define NV 2708
#define INC 1433
#define XCOLS 1472        // padded X/W cols (23*64)
#define UDIM 2752         // padded U dims (43*64)
#define PSTR 2728         // pbuf stride in shorts
#define BSTR 2752
#define SLAB ((size_t)(2752*64))   // fp32 partial slab
#define MWPR 88
#define NSP 4             // proj split-K chunks for K/V (K-chunk 384; last 320)
#define NSU 11            // gemmU split-K chunks (2752 = 10*256 + 192)

typedef __attribute__((ext_vector_type(8))) short bf16x8;
typedef __attribute__((ext_vector_type(4))) float f32x4;
typedef __attribute__((ext_vector_type(4))) unsigned short u16x4;

__device__ __forceinline__ unsigned short f2bf(float f){
  union { float f; unsigned int i; } v; v.f = f;
  return (unsigned short)((v.i + 0x7fffu + ((v.i >> 16) & 1u)) >> 16);  // RNE
}

// convert one fp32 row (INC elems, 4B-aligned base) to bf16 with zero pad to
// XCOLS. float2 via parity shift: src+sh is 8B-aligned (sh in {0,1}).
__device__ __forceinline__ void conv_row(const float* __restrict__ src,
                                         unsigned short* __restrict__ dst, int tid){
  const int sh = ((unsigned int)((size_t)src >> 2)) & 1;
  if (tid == 0){ int ce = sh ? 0 : (INC - 1); dst[ce] = f2bf(src[ce]); }
  const float2* s2 = (const float2*)(src + sh);
  for (int c2 = tid; c2 < (INC - 1)/2; c2 += 256){   // 716 pairs
    float2 v = s2[c2];
    int c = sh + c2*2;
    dst[c]     = f2bf(v.x);
    dst[c + 1] = f2bf(v.y);
  }
  for (int c = INC + tid; c < XCOLS; c += 256) dst[c] = 0;
}

// ====== convert_all: ONLY X/W rows (the data proj depends on). =============
__global__ __launch_bounds__(256) void convert_all(
    const float* __restrict__ X, const float* __restrict__ WK,
    const float* __restrict__ WQ, const float* __restrict__ WV,
    unsigned short* __restrict__ Xbf, unsigned short* __restrict__ Wbf)
{
  const int bx = blockIdx.x;
  const int tid = threadIdx.x;
  if (bx < 2752){                      // X row (float2 parity trick)
    const int row = bx;
    unsigned short* dst = Xbf + (size_t)row*XCOLS;
    if (row < NV){
      conv_row(X + (size_t)row*INC, dst, tid);
    } else {
      u16x4 zz = {0,0,0,0};
      for (int c4 = tid; c4 < XCOLS/4; c4 += 256) *(u16x4*)(dst + c4*4) = zz;
    }
  } else {                             // W row (192 rows)
    const int row = bx - 2752;
    const float* s = (row < 64) ? WK : (row < 128) ? WQ : WV;
    conv_row(s + (size_t)(row & 63)*INC, Wbf + (size_t)row*XCOLS, tid);
  }
}

// ===== proj (+overlapped A/U conversion). grid (467, 4, 3). =================
// bx <  86 : {K,Q,V} = Xbf @ Wbf^T tiles. K (z=0)/V (z=2): split-K partials
//            (slabs 0-3 / 4-7). Q (z=1): s==0 runs FULL-K (23 iters) and
//            writes QT16 bf16 directly; s>0 exits.
// bx in [86,312): A row -> bitmask (slot = y*3+z picks the row).
// bx >= 312 : U 64x64 tile -> Ubf + UTbf (bf16). Consumers are 1-2 launches
//             downstream; stream order guarantees visibility.
__global__ __launch_bounds__(256) void proj(
    const unsigned short* __restrict__ Xbf, const unsigned short* __restrict__ Wbf,
    const float* __restrict__ U, const int* __restrict__ A,
    float* __restrict__ part, unsigned short* __restrict__ QT16,
    unsigned short* __restrict__ Ubf, unsigned short* __restrict__ UTbf,
    unsigned int* __restrict__ Abits)
{
  __shared__ __align__(16) char smem[17408];   // union: At+Bt (13.8K) | tpose (17K)
  const int tid = threadIdx.x;
  const int bx = blockIdx.x;
  const int s = blockIdx.y, z = blockIdx.z;

  if (bx >= 86){
    const int slot = s*3 + z;                  // 12 slots per x
    if (bx < 312){                             // ---- A-bitmask row
      const int i = (bx - 86)*12 + slot;
      if (i < NV){
        const int lane = tid & 63, wave = tid >> 6;
        const int* arow = A + (size_t)i*NV;
        unsigned int* drow = Abits + (size_t)i*MWPR;
        for (int g = wave; g < 11; g += 4){
          int base = g*256 + lane*4;
          int4 v = make_int4(0,0,0,0);
          if (base < NV) v = *(const int4*)(arow + base);
          unsigned long long m0 = __ballot(v.x != 0);
          unsigned long long m1 = __ballot(v.y != 0);
          unsigned long long m2 = __ballot(v.z != 0);
          unsigned long long m3 = __ballot(v.w != 0);
          if (lane < 8){
            unsigned long long mm = (lane < 2) ? m0 : (lane < 4) ? m1 : (lane < 6) ? m2 : m3;
            drow[g*8 + lane] = (lane & 1) ? (unsigned int)(mm >> 32) : (unsigned int)mm;
          }
        }
      }
    } else {                                   // ---- U 64x64 tile
      const int t = (bx - 312)*12 + slot;
      if (t < 1849){
        float* tpose = (float*)smem;           // [64][68]
        const int tx = t % 43, ty = t / 43;
        const int r0 = ty*64, c0 = tx*64;
        #pragma unroll
        for (int j = 0; j < 4; j++){
          int row = j*16 + (tid >> 4);
          int c4  = (tid & 15)*4;
          float4 v = make_float4(0.f,0.f,0.f,0.f);
          if (r0 + row < NV && c0 + c4 < NV)   // NV%4==0: float4 fully valid
            v = *(const float4*)(U + (size_t)(r0+row)*NV + c0 + c4);
          *(float4*)&tpose[row*68 + c4] = v;
          u16x4 h = { f2bf(v.x), f2bf(v.y), f2bf(v.z), f2bf(v.w) };
          *(u16x4*)(Ubf + (size_t)(r0+row)*UDIM + c0 + c4) = h;
        }
        __syncthreads();
        const int i = tid >> 2;
        #pragma unroll
        for (int j = 0; j < 4; j++){
          int kk = ((tid & 3) + j*4)*4;
          u16x4 h = { f2bf(tpose[(kk+0)*68 + i]), f2bf(tpose[(kk+1)*68 + i]),
                      f2bf(tpose[(kk+2)*68 + i]), f2bf(tpose[(kk+3)*68 + i]) };
          *(u16x4*)(UTbf + (size_t)(c0+i)*UDIM + r0 + kk) = h;
        }
      }
    }
    return;
  }

  // ---- GEMM tile
  const bool isQ = (z == 1);
  if (isQ && s) return;
  unsigned short* At = (unsigned short*)smem;            // 32*72
  unsigned short* Bt = (unsigned short*)(smem + 4608);   // 64*72
  const int lane = tid & 63, wave = tid >> 6, quad = lane >> 4, lr = lane & 15;
  const int m0 = bx * 32;
  const int kbeg = isQ ? 0 : s * 384;
  const int kend = isQ ? XCOLS : min(kbeg + 384, XCOLS);  // K/V last chunk 320
  const int wm = (wave & 1) * 16, wn = (wave >> 1) * 32;
  const unsigned short* Wz = Wbf + (size_t)z*64*XCOLS;
  const int arow = tid >> 3, aseg = tid & 7;
  const int brow = tid >> 2, bseg = tid & 3;
  f32x4 acc[2] = {};

  for (int k0 = kbeg; k0 < kend; k0 += 64){
    *(bf16x8*)&At[arow*72 + aseg*8] =
        *(const bf16x8*)(Xbf + (size_t)(m0+arow)*XCOLS + k0 + aseg*8);
    {
      const unsigned short* b = Wz + (size_t)brow*XCOLS + k0 + bseg*16;
      *(bf16x8*)&Bt[brow*72 + bseg*16]     = *(const bf16x8*)(b);
      *(bf16x8*)&Bt[brow*72 + bseg*16 + 8] = *(const bf16x8*)(b + 8);
    }
    __syncthreads();
    #pragma unroll
    for (int ks = 0; ks < 2; ks++){
      bf16x8 af = *(const bf16x8*)&At[(wm + lr)*72 + ks*32 + quad*8];
      bf16x8 bv[2];
      #pragma unroll
      for (int t = 0; t < 2; t++)
        bv[t] = *(const bf16x8*)&Bt[(wn + t*16 + lr)*72 + ks*32 + quad*8];
      #pragma unroll
      for (int t = 0; t < 2; t++)
        acc[t] = __builtin_amdgcn_mfma_f32_16x16x32_bf16(af, bv[t], acc[t], 0, 0, 0);
    }
    __syncthreads();
  }
  if (isQ){
    #pragma unroll
    for (int t = 0; t < 2; t++)
      #pragma unroll
      for (int e = 0; e < 4; e++){
        int m = m0 + wm + quad*4 + e;
        int c = wn + t*16 + lr;
        QT16[(size_t)c*BSTR + m] = f2bf(acc[t][e]);   // Xbf pad rows are 0
      }
  } else {
    float* dst = part + (size_t)((z == 2 ? NSP : 0) + s) * SLAB;
    #pragma unroll
    for (int t = 0; t < 2; t++)
      #pragma unroll
      for (int e = 0; e < 4; e++)
        dst[(size_t)(m0 + wm + quad*4 + e)*64 + wn + t*16 + lr] = acc[t][e];
  }
}

// K16f frag-linear ; VTf frag-linear. grid (688, 2). (Q handled in proj.)
__global__ __launch_bounds__(256) void reduce_proj(
    const float* __restrict__ part, unsigned short* __restrict__ K16f,
    unsigned short* __restrict__ VTf)
{
  int idx = blockIdx.x*256 + threadIdx.x;       // < 2752*64
  int zv = blockIdx.y;                          // 0=K, 1=V
  int m = idx >> 6, c = idx & 63;
  const float* base = part + (size_t)(zv ? NSP : 0)*SLAB + idx;
  float v = 0.f;
  #pragma unroll
  for (int s = 0; s < NSP; s++) v += base[s*SLAB];
  if (m < 2720){
    unsigned short h = (m < NV) ? f2bf(v) : (unsigned short)0;
    if (zv == 0) K16f[((m>>4)*2 + (c>>5))*512 + (m&15)*32 + (c&31)] = h;
    else         VTf[(m>>5)*2048 + c*32 + (m&31)] = h;
  }
}

// ===== gemmU: partials of Arow @ Bcm^T. grid (86, 11). 32-row tiles. ========
// Used twice: G = UTbf @ Q  (Bcm = QT16 [c][k])  and  F = Ubf @ G2 (Bcm = G2T).
__global__ __launch_bounds__(256) void gemmU(
    const unsigned short* __restrict__ Arow, const unsigned short* __restrict__ Bcm,
    float* __restrict__ part)
{
  __shared__ __align__(16) unsigned short At[32*72];
  __shared__ __align__(16) unsigned short Bt[64*72];
  const int tid = threadIdx.x;
  const int lane = tid & 63, wave = tid >> 6, quad = lane >> 4, lr = lane & 15;
  const int m0 = blockIdx.x * 32;
  const int s  = blockIdx.y;
  const int kbeg = s * 256, kend = min(kbeg + 256, UDIM);   // last chunk 192
  const int wm = (wave & 1) * 16, wn = (wave >> 1) * 32;
  const int arow = tid >> 3, aseg = tid & 7;
  const int bc = tid >> 2, bseg = tid & 3;
  f32x4 acc[2] = {};

  for (int k0 = kbeg; k0 < kend; k0 += 64){
    *(bf16x8*)&At[arow*72 + aseg*8] =
        *(const bf16x8*)(Arow + (size_t)(m0+arow)*UDIM + k0 + aseg*8);
    {
      const unsigned short* b = Bcm + (size_t)bc*BSTR + k0 + bseg*16;
      *(bf16x8*)&Bt[bc*72 + bseg*16]     = *(const bf16x8*)(b);
      *(bf16x8*)&Bt[bc*72 + bseg*16 + 8] = *(const bf16x8*)(b + 8);
    }
    __syncthreads();
    #pragma unroll
    for (int ks = 0; ks < 2; ks++){
      bf16x8 af = *(const bf16x8*)&At[(wm + lr)*72 + ks*32 + quad*8];
      bf16x8 bv[2];
      #pragma unroll
      for (int t = 0; t < 2; t++)
        bv[t] = *(const bf16x8*)&Bt[(wn + t*16 + lr)*72 + ks*32 + quad*8];
      #pragma unroll
      for (int t = 0; t < 2; t++)
        acc[t] = __builtin_amdgcn_mfma_f32_16x16x32_bf16(af, bv[t], acc[t], 0, 0, 0);
    }
    __syncthreads();
  }
  float* dst = part + (size_t)s * SLAB;
  #pragma unroll
  for (int t = 0; t < 2; t++)
    #pragma unroll
    for (int e = 0; e < 4; e++)
      dst[(size_t)(m0 + wm + quad*4 + e)*64 + wn + t*16 + lr] = acc[t][e];
}

// G2T16[c][m] = bf16(G[m][c] * lmbd[m]/64), zero pads. grid 688.
__global__ __launch_bounds__(256) void reduce_g(
    const float* __restrict__ part, const float* __restrict__ lm,
    unsigned short* __restrict__ G2T)
{
  int idx = blockIdx.x*256 + threadIdx.x;
  int m = idx >> 6, c = idx & 63;
  const float* base = part + idx;
  float v = 0.f;
  #pragma unroll
  for (int s = 0; s < NSU; s++) v += base[s*SLAB];
  unsigned short h = 0;
  if (m < NV) h = f2bf(v * lm[m] * (1.0f/64.0f));
  G2T[(size_t)c*BSTR + m] = h;
}

// ====== fused: reduce-F + |F K^T| -> masked exp + row-sum -> P V ============
// 16 rows/block, 512 threads (8 waves), 170 blocks (1 block/CU, no tail).
__global__ __launch_bounds__(512) void fused_attn(
    const float* __restrict__ partF, const unsigned short* __restrict__ K16f,
    const unsigned int* __restrict__ Abits, const unsigned short* __restrict__ VTf,
    float* __restrict__ Hout)
{
  __shared__ __align__(16) unsigned short pbuf[16*PSTR];   // 87.3 KB
  __shared__ __align__(16) unsigned short fbuf[16*64];     // 2 KB
  __shared__ unsigned int mrow[16*MWPR];                   // 5.6 KB
  __shared__ float swave[8][16];
  __shared__ float rinv[16];
  __shared__ __align__(16) float obuf[4][256];             // 4 KB
  const int tid  = threadIdx.x;
  const int lane = tid & 63, wave = tid >> 6;
  const int quad = lane >> 4, lr = lane & 15;
  const int i0 = blockIdx.x * 16;

  // stage F rows (sum 11 slabs; rows >= NV are zero in part)
  #pragma unroll
  for (int h = 0; h < 2; h++){
    int idx = h*512 + tid;              // < 1024
    const float* base = partF + (size_t)(i0 + (idx >> 6))*64 + (idx & 63);
    float v = 0.f;
    #pragma unroll
    for (int s = 0; s < NSU; s++) v += base[s*SLAB];
    fbuf[idx] = f2bf(v);
  }
  for (int idx = tid; idx < 16*MWPR; idx += 512){
    int r = idx / MWPR;
    unsigned int v = 0;
    if (i0 + r < NV) v = Abits[(size_t)(i0 + r)*MWPR + (idx - r*MWPR)];
    mrow[idx] = v;
  }
  __syncthreads();

  const bf16x8 af0 = *(const bf16x8*)&fbuf[lr*64 + quad*8];
  const bf16x8 af1 = *(const bf16x8*)&fbuf[lr*64 + 32 + quad*8];
  float psum[4] = {0.f, 0.f, 0.f, 0.f};
  {
    int t = wave;
    const unsigned short* kb = K16f + t*1024 + lr*32 + quad*8;
    bf16x8 b0 = *(const bf16x8*)(kb);
    bf16x8 b1 = *(const bf16x8*)(kb + 512);
    while (t < 170){
      int tn = t + 8;
      bf16x8 n0 = b0, n1 = b1;
      if (tn < 170){
        const unsigned short* nb = K16f + tn*1024 + lr*32 + quad*8;
        n0 = *(const bf16x8*)(nb);
        n1 = *(const bf16x8*)(nb + 512);
      }
      f32x4 sv0 = {}, sv1 = {};
      sv0 = __builtin_amdgcn_mfma_f32_16x16x32_bf16(af0, b0, sv0, 0, 0, 0);
      sv1 = __builtin_amdgcn_mfma_f32_16x16x32_bf16(af1, b1, sv1, 0, 0, 0);
      f32x4 sv = sv0 + sv1;
      {
        int col = t*16 + lr;
        int ss = col & 255, ll = ss >> 2;
        int wsh = (col >> 8)*8 + (ss & 3)*2 + (ll >> 5);
        int bit = ll & 31;
        #pragma unroll
        for (int e = 0; e < 4; e++){
          int r = quad*4 + e;
          float p = 0.f;
          if ((mrow[r*MWPR + wsh] >> bit) & 1u) p = __expf(fabsf(sv[e]));
          psum[e] += p;
          pbuf[r*PSTR + col] = f2bf(p);
        }
      }
      b0 = n0; b1 = n1; t = tn;
    }
  }
  #pragma unroll
  for (int e = 0; e < 4; e++){
    float v = psum[e];
    #pragma unroll
    for (int o = 1; o <= 8; o <<= 1) v += __shfl_xor(v, o, 64);
    if (lr == 0) swave[wave][quad*4 + e] = v;
  }
  __syncthreads();
  if (tid < 16){
    float s = 0.f;
    #pragma unroll
    for (int w = 0; w < 8; w++) s += swave[w][tid];
    rinv[tid] = (s > 0.f) ? (1.f/s) : 0.f;
  }
  __syncthreads();

  const int c0 = (wave & 3) * 16;
  const int ktbeg = (wave >> 2) ? 43 : 0;
  const int ktend = (wave >> 2) ? 85 : 43;
  f32x4 acc = {};
  {
    bf16x8 bv = *(const bf16x8*)&VTf[ktbeg*2048 + (c0 + lr)*32 + quad*8];
    for (int kt = ktbeg; kt < ktend; kt++){
      bf16x8 bn = bv;
      if (kt + 1 < ktend) bn = *(const bf16x8*)&VTf[(kt+1)*2048 + (c0 + lr)*32 + quad*8];
      bf16x8 af = *(const bf16x8*)&pbuf[lr*PSTR + kt*32 + quad*8];
      acc = __builtin_amdgcn_mfma_f32_16x16x32_bf16(af, bv, acc, 0, 0, 0);
      bv = bn;
    }
  }
  if (wave >= 4) *(f32x4*)&obuf[wave & 3][lane*4] = acc;
  __syncthreads();
  if (wave < 4){
    f32x4 o = *(const f32x4*)&obuf[wave][lane*4];
    acc += o;
    #pragma unroll
    for (int e = 0; e < 4; e++){
      int r = quad*4 + e;
      int i = i0 + r;
      if (i < NV) Hout[(size_t)i*64 + c0 + lr] = acc[e] * rinv[r];
    }
  }
}

extern "C" void kernel_launch(void* const* d_in, const int* in_sizes, int n_in,
                              void* d_out, int out_size, void* d_ws, size_t ws_size,
                              hipStream_t stream){
  (void)in_sizes; (void)n_in; (void)out_size; (void)ws_size;
  const float* X  = (const float*)d_in[0];
  const int*   A  = (const int*)d_in[1];
  const float* U  = (const float*)d_in[2];
  const float* WK = (const float*)d_in[3];
  const float* WQ = (const float*)d_in[4];
  const float* WV = (const float*)d_in[5];
  const float* lm = (const float*)d_in[6];

  char* ws = (char*)d_ws;
  size_t off = 0;
  auto alloc = [&](size_t bytes){ size_t o = off; off = (off + bytes + 255) & ~(size_t)255; return o; };
  float*          part = (float*)(ws + alloc(11*SLAB*4));                      // 7.75 MB (K/V, then G, then F)
  unsigned short* Ubf  = (unsigned short*)(ws + alloc((size_t)UDIM*UDIM*2));   // 15.15 MB
  unsigned short* UTbf = (unsigned short*)(ws + alloc((size_t)UDIM*UDIM*2));   // 15.15 MB
  unsigned short* Xbf  = (unsigned short*)(ws + alloc((size_t)UDIM*XCOLS*2));  // 8.10 MB
  unsigned short* Wbf  = (unsigned short*)(ws + alloc((size_t)192*XCOLS*2));
  unsigned short* K16f = (unsigned short*)(ws + alloc((size_t)170*1024*2));
  unsigned short* QT16 = (unsigned short*)(ws + alloc((size_t)64*BSTR*2));
  unsigned short* G2T  = (unsigned short*)(ws + alloc((size_t)64*BSTR*2));
  unsigned short* VTf  = (unsigned short*)(ws + alloc((size_t)85*2048*2));
  unsigned int*   Abits= (unsigned int*)(ws + alloc((size_t)NV*MWPR*4));
  // total ~50 MB

  convert_all<<<dim3(2944), 256, 0, stream>>>(X, WK, WQ, WV, Xbf, Wbf);
  proj<<<dim3(467, NSP, 3), 256, 0, stream>>>(Xbf, Wbf, U, A, part, QT16,
                                              Ubf, UTbf, Abits);
  reduce_proj<<<dim3(688, 2), 256, 0, stream>>>(part, K16f, VTf);
  gemmU<<<dim3(86, NSU), 256, 0, stream>>>(UTbf, QT16, part);     // G partials
  reduce_g<<<dim3(688), 256, 0, stream>>>(part, lm, G2T);
  gemmU<<<dim3(86, NSU), 256, 0, stream>>>(Ubf, G2T, part);       // F partials
  fused_attn<<<dim3(170), 512, 0, stream>>>(part, K16f, Abits, VTf, (float*)d_out);
}

// Round 11
// 179.236 us; speedup vs baseline: 1.0102x; 1.0035x over previous
//
#include <hip/hip_runtime.h>

#define NV 2708
#define INC 1433
#define XCOLS 1472        // padded X/W cols (23*64)
#define UDIM 2752         // padded U dims (43*64)
#define PSTR 2728         // pbuf stride in shorts
#define BSTR 2752
#define SLAB ((size_t)(2752*64))   // fp32 partial slab
#define MWPR 88
#define NSP 4             // proj split-K chunks for K/V (K-chunk 384; last 320)
#define NSU 11            // gemmU split-K chunks (2752 = 10*256 + 192)

typedef __attribute__((ext_vector_type(8))) short bf16x8;
typedef __attribute__((ext_vector_type(4))) float f32x4;
typedef __attribute__((ext_vector_type(4))) unsigned short u16x4;

__device__ __forceinline__ unsigned short f2bf(float f){
  union { float f; unsigned int i; } v; v.f = f;
  return (unsigned short)((v.i + 0x7fffu + ((v.i >> 16) & 1u)) >> 16);  // RNE
}

// convert one fp32 row (INC elems, 4B-aligned base) to bf16 with zero pad to
// XCOLS. float2 via parity shift: src+sh is 8B-aligned (sh in {0,1}).
__device__ __forceinline__ void conv_row(const float* __restrict__ src,
                                         unsigned short* __restrict__ dst, int tid){
  const int sh = ((unsigned int)((size_t)src >> 2)) & 1;
  if (tid == 0){ int ce = sh ? 0 : (INC - 1); dst[ce] = f2bf(src[ce]); }
  const float2* s2 = (const float2*)(src + sh);
  for (int c2 = tid; c2 < (INC - 1)/2; c2 += 256){   // 716 pairs
    float2 v = s2[c2];
    int c = sh + c2*2;
    dst[c]     = f2bf(v.x);
    dst[c + 1] = f2bf(v.y);
  }
  for (int c = INC + tid; c < XCOLS; c += 256) dst[c] = 0;
}

// ====== convert_all: X/W/A one-row blocks + U 64x64 tiles (Ubf AND UTbf) ====
__global__ __launch_bounds__(256) void convert_all(
    const float* __restrict__ X, const float* __restrict__ WK,
    const float* __restrict__ WQ, const float* __restrict__ WV,
    const float* __restrict__ U, const int* __restrict__ A,
    unsigned short* __restrict__ Xbf, unsigned short* __restrict__ Wbf,
    unsigned short* __restrict__ Ubf, unsigned short* __restrict__ UTbf,
    unsigned int* __restrict__ Abits)
{
  __shared__ __align__(16) float tpose[64][68];   // 17.4 KB (U-tile branch)
  const int bx = blockIdx.x;
  const int tid = threadIdx.x;
  if (bx < 2752){                      // X row (float2 parity trick)
    const int row = bx;
    unsigned short* dst = Xbf + (size_t)row*XCOLS;
    if (row < NV){
      conv_row(X + (size_t)row*INC, dst, tid);
    } else {
      u16x4 zz = {0,0,0,0};
      for (int c4 = tid; c4 < XCOLS/4; c4 += 256) *(u16x4*)(dst + c4*4) = zz;
    }
  } else if (bx < 2944){               // W row (192 rows)
    const int row = bx - 2752;
    const float* s = (row < 64) ? WK : (row < 128) ? WQ : WV;
    conv_row(s + (size_t)(row & 63)*INC, Wbf + (size_t)row*XCOLS, tid);
  } else if (bx < 5652){               // A row -> bitmask (int4, grouped layout)
    const int i = bx - 2944;
    const int lane = tid & 63, wave = tid >> 6;
    const int* arow = A + (size_t)i*NV;
    unsigned int* drow = Abits + (size_t)i*MWPR;
    for (int g = wave; g < 11; g += 4){
      int base = g*256 + lane*4;
      int4 v = make_int4(0,0,0,0);
      if (base < NV) v = *(const int4*)(arow + base);
      unsigned long long m0 = __ballot(v.x != 0);
      unsigned long long m1 = __ballot(v.y != 0);
      unsigned long long m2 = __ballot(v.z != 0);
      unsigned long long m3 = __ballot(v.w != 0);
      if (lane < 8){
        unsigned long long mm = (lane < 2) ? m0 : (lane < 4) ? m1 : (lane < 6) ? m2 : m3;
        drow[g*8 + lane] = (lane & 1) ? (unsigned int)(mm >> 32) : (unsigned int)mm;
      }
    }
  } else {                             // U 64x64 tile -> Ubf rows + UTbf rows
    const int t = bx - 5652;           // < 1849
    const int tx = t % 43, ty = t / 43;
    const int r0 = ty*64, c0 = tx*64;
    #pragma unroll
    for (int j = 0; j < 4; j++){
      int row = j*16 + (tid >> 4);     // U row within tile
      int c4  = (tid & 15)*4;          // U col within tile
      float4 v = make_float4(0.f,0.f,0.f,0.f);
      if (r0 + row < NV && c0 + c4 < NV)        // NV%4==0: float4 fully valid
        v = *(const float4*)(U + (size_t)(r0+row)*NV + c0 + c4);
      *(float4*)&tpose[row][c4] = v;
      u16x4 h = { f2bf(v.x), f2bf(v.y), f2bf(v.z), f2bf(v.w) };
      *(u16x4*)(Ubf + (size_t)(r0+row)*UDIM + c0 + c4) = h;
    }
    __syncthreads();
    const int i = tid >> 2;            // UT row within tile (UT row c0+i)
    #pragma unroll
    for (int j = 0; j < 4; j++){
      int kk = ((tid & 3) + j*4)*4;    // UT col (k) start
      u16x4 h = { f2bf(tpose[kk+0][i]), f2bf(tpose[kk+1][i]),
                  f2bf(tpose[kk+2][i]), f2bf(tpose[kk+3][i]) };
      *(u16x4*)(UTbf + (size_t)(c0+i)*UDIM + r0 + kk) = h;
    }
  }
}

// ===== proj: {K,Q,V} = Xbf @ Wbf^T. grid (86,4,3). ==========================
// K (z=0)/V (z=2): split-K partials (slabs 0-3 / 4-7).
// Q (z=1): s==0 runs FULL-K (23 iters) and writes QT16 bf16 directly.
__global__ __launch_bounds__(256) void proj(
    const unsigned short* __restrict__ Xbf, const unsigned short* __restrict__ Wbf,
    float* __restrict__ part, unsigned short* __restrict__ QT16)
{
  __shared__ __align__(16) unsigned short At[32*72];
  __shared__ __align__(16) unsigned short Bt[64*72];
  const int tid = threadIdx.x;
  const int s = blockIdx.y, z = blockIdx.z;
  const bool isQ = (z == 1);
  if (isQ && s) return;
  const int lane = tid & 63, wave = tid >> 6, quad = lane >> 4, lr = lane & 15;
  const int m0 = blockIdx.x * 32;
  const int kbeg = isQ ? 0 : s * 384;
  const int kend = isQ ? XCOLS : min(kbeg + 384, XCOLS);  // K/V last chunk 320
  const int wm = (wave & 1) * 16, wn = (wave >> 1) * 32;
  const unsigned short* Wz = Wbf + (size_t)z*64*XCOLS;
  const int arow = tid >> 3, aseg = tid & 7;
  const int brow = tid >> 2, bseg = tid & 3;
  f32x4 acc[2] = {};

  for (int k0 = kbeg; k0 < kend; k0 += 64){
    *(bf16x8*)&At[arow*72 + aseg*8] =
        *(const bf16x8*)(Xbf + (size_t)(m0+arow)*XCOLS + k0 + aseg*8);
    {
      const unsigned short* b = Wz + (size_t)brow*XCOLS + k0 + bseg*16;
      *(bf16x8*)&Bt[brow*72 + bseg*16]     = *(const bf16x8*)(b);
      *(bf16x8*)&Bt[brow*72 + bseg*16 + 8] = *(const bf16x8*)(b + 8);
    }
    __syncthreads();
    #pragma unroll
    for (int ks = 0; ks < 2; ks++){
      bf16x8 af = *(const bf16x8*)&At[(wm + lr)*72 + ks*32 + quad*8];
      bf16x8 bv[2];
      #pragma unroll
      for (int t = 0; t < 2; t++)
        bv[t] = *(const bf16x8*)&Bt[(wn + t*16 + lr)*72 + ks*32 + quad*8];
      #pragma unroll
      for (int t = 0; t < 2; t++)
        acc[t] = __builtin_amdgcn_mfma_f32_16x16x32_bf16(af, bv[t], acc[t], 0, 0, 0);
    }
    __syncthreads();
  }
  if (isQ){
    #pragma unroll
    for (int t = 0; t < 2; t++)
      #pragma unroll
      for (int e = 0; e < 4; e++){
        int m = m0 + wm + quad*4 + e;
        int c = wn + t*16 + lr;
        QT16[(size_t)c*BSTR + m] = f2bf(acc[t][e]);   // Xbf pad rows are 0
      }
  } else {
    float* dst = part + (size_t)((z == 2 ? NSP : 0) + s) * SLAB;
    #pragma unroll
    for (int t = 0; t < 2; t++)
      #pragma unroll
      for (int e = 0; e < 4; e++)
        dst[(size_t)(m0 + wm + quad*4 + e)*64 + wn + t*16 + lr] = acc[t][e];
  }
}

// ===== gemmG: G-partials = UTbf @ Q. grid (86, 11). Folds reduce_proj. ======
// Prologue: 946 blocks grid-stride the K/V partial slabs (0-3 K, 4-7 V) into
// K16f/VTf bf16 final layouts. Consumer (fused_attn) is 3 launches downstream;
// stream order guarantees visibility. Sum order identical to old reduce_proj.
__global__ __launch_bounds__(256) void gemmG(
    const unsigned short* __restrict__ UTbf, const unsigned short* __restrict__ QT16,
    const float* __restrict__ part,
    unsigned short* __restrict__ K16f, unsigned short* __restrict__ VTf,
    float* __restrict__ partG)
{
  __shared__ __align__(16) unsigned short At[32*72];
  __shared__ __align__(16) unsigned short Bt[64*72];
  const int tid = threadIdx.x;
  const int lane = tid & 63, wave = tid >> 6, quad = lane >> 4, lr = lane & 15;
  const int m0 = blockIdx.x * 32;
  const int s  = blockIdx.y;
  const int kbeg = s * 256, kend = min(kbeg + 256, UDIM);   // last chunk 192
  const int wm = (wave & 1) * 16, wn = (wave >> 1) * 32;
  const int arow = tid >> 3, aseg = tid & 7;
  const int bc = tid >> 2, bseg = tid & 3;
  f32x4 acc[2] = {};

  // ---- prologue: fold K/V partials into final bf16 layouts (once, global)
  {
    int bid = blockIdx.y*86 + blockIdx.x;
    for (int i = bid*256 + tid; i < 2*176128; i += 946*256){
      int isV = (i >= 176128) ? 1 : 0;
      int idx = i - isV*176128;
      const float* base = part + (size_t)(isV ? NSP : 0)*SLAB + idx;
      float v = 0.f;
      #pragma unroll
      for (int s2 = 0; s2 < NSP; s2++) v += base[s2*SLAB];
      int m = idx >> 6, c = idx & 63;
      if (m < 2720){
        unsigned short h = (m < NV) ? f2bf(v) : (unsigned short)0;
        if (!isV) K16f[((m>>4)*2 + (c>>5))*512 + (m&15)*32 + (c&31)] = h;
        else      VTf[(m>>5)*2048 + c*32 + (m&31)] = h;
      }
    }
  }

  for (int k0 = kbeg; k0 < kend; k0 += 64){
    *(bf16x8*)&At[arow*72 + aseg*8] =
        *(const bf16x8*)(UTbf + (size_t)(m0+arow)*UDIM + k0 + aseg*8);
    {
      const unsigned short* b = QT16 + (size_t)bc*BSTR + k0 + bseg*16;
      *(bf16x8*)&Bt[bc*72 + bseg*16]     = *(const bf16x8*)(b);
      *(bf16x8*)&Bt[bc*72 + bseg*16 + 8] = *(const bf16x8*)(b + 8);
    }
    __syncthreads();
    #pragma unroll
    for (int ks = 0; ks < 2; ks++){
      bf16x8 af = *(const bf16x8*)&At[(wm + lr)*72 + ks*32 + quad*8];
      bf16x8 bv[2];
      #pragma unroll
      for (int t = 0; t < 2; t++)
        bv[t] = *(const bf16x8*)&Bt[(wn + t*16 + lr)*72 + ks*32 + quad*8];
      #pragma unroll
      for (int t = 0; t < 2; t++)
        acc[t] = __builtin_amdgcn_mfma_f32_16x16x32_bf16(af, bv[t], acc[t], 0, 0, 0);
    }
    __syncthreads();
  }
  float* dst = partG + (size_t)s * SLAB;
  #pragma unroll
  for (int t = 0; t < 2; t++)
    #pragma unroll
    for (int e = 0; e < 4; e++)
      dst[(size_t)(m0 + wm + quad*4 + e)*64 + wn + t*16 + lr] = acc[t][e];
}

// ===== gemmU: partials of Arow @ Bcm^T. grid (86, 11). (F = Ubf @ G2) =======
__global__ __launch_bounds__(256) void gemmU(
    const unsigned short* __restrict__ Arow, const unsigned short* __restrict__ Bcm,
    float* __restrict__ part)
{
  __shared__ __align__(16) unsigned short At[32*72];
  __shared__ __align__(16) unsigned short Bt[64*72];
  const int tid = threadIdx.x;
  const int lane = tid & 63, wave = tid >> 6, quad = lane >> 4, lr = lane & 15;
  const int m0 = blockIdx.x * 32;
  const int s  = blockIdx.y;
  const int kbeg = s * 256, kend = min(kbeg + 256, UDIM);   // last chunk 192
  const int wm = (wave & 1) * 16, wn = (wave >> 1) * 32;
  const int arow = tid >> 3, aseg = tid & 7;
  const int bc = tid >> 2, bseg = tid & 3;
  f32x4 acc[2] = {};

  for (int k0 = kbeg; k0 < kend; k0 += 64){
    *(bf16x8*)&At[arow*72 + aseg*8] =
        *(const bf16x8*)(Arow + (size_t)(m0+arow)*UDIM + k0 + aseg*8);
    {
      const unsigned short* b = Bcm + (size_t)bc*BSTR + k0 + bseg*16;
      *(bf16x8*)&Bt[bc*72 + bseg*16]     = *(const bf16x8*)(b);
      *(bf16x8*)&Bt[bc*72 + bseg*16 + 8] = *(const bf16x8*)(b + 8);
    }
    __syncthreads();
    #pragma unroll
    for (int ks = 0; ks < 2; ks++){
      bf16x8 af = *(const bf16x8*)&At[(wm + lr)*72 + ks*32 + quad*8];
      bf16x8 bv[2];
      #pragma unroll
      for (int t = 0; t < 2; t++)
        bv[t] = *(const bf16x8*)&Bt[(wn + t*16 + lr)*72 + ks*32 + quad*8];
      #pragma unroll
      for (int t = 0; t < 2; t++)
        acc[t] = __builtin_amdgcn_mfma_f32_16x16x32_bf16(af, bv[t], acc[t], 0, 0, 0);
    }
    __syncthreads();
  }
  float* dst = part + (size_t)s * SLAB;
  #pragma unroll
  for (int t = 0; t < 2; t++)
    #pragma unroll
    for (int e = 0; e < 4; e++)
      dst[(size_t)(m0 + wm + quad*4 + e)*64 + wn + t*16 + lr] = acc[t][e];
}

// G2T16[c][m] = bf16(G[m][c] * lmbd[m]/64), zero pads. grid 688.
__global__ __launch_bounds__(256) void reduce_g(
    const float* __restrict__ partG, const float* __restrict__ lm,
    unsigned short* __restrict__ G2T)
{
  int idx = blockIdx.x*256 + threadIdx.x;
  int m = idx >> 6, c = idx & 63;
  const float* base = partG + idx;
  float v = 0.f;
  #pragma unroll
  for (int s = 0; s < NSU; s++) v += base[s*SLAB];
  unsigned short h = 0;
  if (m < NV) h = f2bf(v * lm[m] * (1.0f/64.0f));
  G2T[(size_t)c*BSTR + m] = h;
}

// ====== fused: reduce-F + |F K^T| -> masked exp + row-sum -> P V ============
// 16 rows/block, 512 threads (8 waves), 170 blocks (1 block/CU, no tail).
__global__ __launch_bounds__(512) void fused_attn(
    const float* __restrict__ partF, const unsigned short* __restrict__ K16f,
    const unsigned int* __restrict__ Abits, const unsigned short* __restrict__ VTf,
    float* __restrict__ Hout)
{
  __shared__ __align__(16) unsigned short pbuf[16*PSTR];   // 87.3 KB
  __shared__ __align__(16) unsigned short fbuf[16*64];     // 2 KB
  __shared__ unsigned int mrow[16*MWPR];                   // 5.6 KB
  __shared__ float swave[8][16];
  __shared__ float rinv[16];
  __shared__ __align__(16) float obuf[4][256];             // 4 KB
  const int tid  = threadIdx.x;
  const int lane = tid & 63, wave = tid >> 6;
  const int quad = lane >> 4, lr = lane & 15;
  const int i0 = blockIdx.x * 16;

  // stage F rows (sum 11 slabs; rows >= NV are zero in part)
  #pragma unroll
  for (int h = 0; h < 2; h++){
    int idx = h*512 + tid;              // < 1024
    const float* base = partF + (size_t)(i0 + (idx >> 6))*64 + (idx & 63);
    float v = 0.f;
    #pragma unroll
    for (int s = 0; s < NSU; s++) v += base[s*SLAB];
    fbuf[idx] = f2bf(v);
  }
  for (int idx = tid; idx < 16*MWPR; idx += 512){
    int r = idx / MWPR;
    unsigned int v = 0;
    if (i0 + r < NV) v = Abits[(size_t)(i0 + r)*MWPR + (idx - r*MWPR)];
    mrow[idx] = v;
  }
  __syncthreads();

  const bf16x8 af0 = *(const bf16x8*)&fbuf[lr*64 + quad*8];
  const bf16x8 af1 = *(const bf16x8*)&fbuf[lr*64 + 32 + quad*8];
  float psum[4] = {0.f, 0.f, 0.f, 0.f};
  {
    int t = wave;
    const unsigned short* kb = K16f + t*1024 + lr*32 + quad*8;
    bf16x8 b0 = *(const bf16x8*)(kb);
    bf16x8 b1 = *(const bf16x8*)(kb + 512);
    while (t < 170){
      int tn = t + 8;
      bf16x8 n0 = b0, n1 = b1;
      if (tn < 170){
        const unsigned short* nb = K16f + tn*1024 + lr*32 + quad*8;
        n0 = *(const bf16x8*)(nb);
        n1 = *(const bf16x8*)(nb + 512);
      }
      f32x4 sv0 = {}, sv1 = {};
      sv0 = __builtin_amdgcn_mfma_f32_16x16x32_bf16(af0, b0, sv0, 0, 0, 0);
      sv1 = __builtin_amdgcn_mfma_f32_16x16x32_bf16(af1, b1, sv1, 0, 0, 0);
      f32x4 sv = sv0 + sv1;
      {
        int col = t*16 + lr;
        int ss = col & 255, ll = ss >> 2;
        int wsh = (col >> 8)*8 + (ss & 3)*2 + (ll >> 5);
        int bit = ll & 31;
        #pragma unroll
        for (int e = 0; e < 4; e++){
          int r = quad*4 + e;
          float p = 0.f;
          if ((mrow[r*MWPR + wsh] >> bit) & 1u) p = __expf(fabsf(sv[e]));
          psum[e] += p;
          pbuf[r*PSTR + col] = f2bf(p);
        }
      }
      b0 = n0; b1 = n1; t = tn;
    }
  }
  #pragma unroll
  for (int e = 0; e < 4; e++){
    float v = psum[e];
    #pragma unroll
    for (int o = 1; o <= 8; o <<= 1) v += __shfl_xor(v, o, 64);
    if (lr == 0) swave[wave][quad*4 + e] = v;
  }
  __syncthreads();
  if (tid < 16){
    float s = 0.f;
    #pragma unroll
    for (int w = 0; w < 8; w++) s += swave[w][tid];
    rinv[tid] = (s > 0.f) ? (1.f/s) : 0.f;
  }
  __syncthreads();

  const int c0 = (wave & 3) * 16;
  const int ktbeg = (wave >> 2) ? 43 : 0;
  const int ktend = (wave >> 2) ? 85 : 43;
  f32x4 acc = {};
  {
    bf16x8 bv = *(const bf16x8*)&VTf[ktbeg*2048 + (c0 + lr)*32 + quad*8];
    for (int kt = ktbeg; kt < ktend; kt++){
      bf16x8 bn = bv;
      if (kt + 1 < ktend) bn = *(const bf16x8*)&VTf[(kt+1)*2048 + (c0 + lr)*32 + quad*8];
      bf16x8 af = *(const bf16x8*)&pbuf[lr*PSTR + kt*32 + quad*8];
      acc = __builtin_amdgcn_mfma_f32_16x16x32_bf16(af, bv, acc, 0, 0, 0);
      bv = bn;
    }
  }
  if (wave >= 4) *(f32x4*)&obuf[wave & 3][lane*4] = acc;
  __syncthreads();
  if (wave < 4){
    f32x4 o = *(const f32x4*)&obuf[wave][lane*4];
    acc += o;
    #pragma unroll
    for (int e = 0; e < 4; e++){
      int r = quad*4 + e;
      int i = i0 + r;
      if (i < NV) Hout[(size_t)i*64 + c0 + lr] = acc[e] * rinv[r];
    }
  }
}

extern "C" void kernel_launch(void* const* d_in, const int* in_sizes, int n_in,
                              void* d_out, int out_size, void* d_ws, size_t ws_size,
                              hipStream_t stream){
  (void)in_sizes; (void)n_in; (void)out_size; (void)ws_size;
  const float* X  = (const float*)d_in[0];
  const int*   A  = (const int*)d_in[1];
  const float* U  = (const float*)d_in[2];
  const float* WK = (const float*)d_in[3];
  const float* WQ = (const float*)d_in[4];
  const float* WV = (const float*)d_in[5];
  const float* lm = (const float*)d_in[6];

  char* ws = (char*)d_ws;
  size_t off = 0;
  auto alloc = [&](size_t bytes){ size_t o = off; off = (off + bytes + 255) & ~(size_t)255; return o; };
  float*          part = (float*)(ws + alloc(19*SLAB*4));                      // 13.4 MB (0-7 K/V, 8-18 G; 0-10 reused for F)
  unsigned short* Ubf  = (unsigned short*)(ws + alloc((size_t)UDIM*UDIM*2));   // 15.15 MB
  unsigned short* UTbf = (unsigned short*)(ws + alloc((size_t)UDIM*UDIM*2));   // 15.15 MB
  unsigned short* Xbf  = (unsigned short*)(ws + alloc((size_t)UDIM*XCOLS*2));  // 8.10 MB
  unsigned short* Wbf  = (unsigned short*)(ws + alloc((size_t)192*XCOLS*2));
  unsigned short* K16f = (unsigned short*)(ws + alloc((size_t)170*1024*2));
  unsigned short* QT16 = (unsigned short*)(ws + alloc((size_t)64*BSTR*2));
  unsigned short* G2T  = (unsigned short*)(ws + alloc((size_t)64*BSTR*2));
  unsigned short* VTf  = (unsigned short*)(ws + alloc((size_t)85*2048*2));
  unsigned int*   Abits= (unsigned int*)(ws + alloc((size_t)NV*MWPR*4));
  // total ~56 MB
  float* partG = part + (size_t)8*SLAB;

  convert_all<<<dim3(7501), 256, 0, stream>>>(X, WK, WQ, WV, U, A,
                                              Xbf, Wbf, Ubf, UTbf, Abits);
  proj<<<dim3(86, NSP, 3), 256, 0, stream>>>(Xbf, Wbf, part, QT16);
  gemmG<<<dim3(86, NSU), 256, 0, stream>>>(UTbf, QT16, part, K16f, VTf, partG);
  reduce_g<<<dim3(688), 256, 0, stream>>>(partG, lm, G2T);
  gemmU<<<dim3(86, NSU), 256, 0, stream>>>(Ubf, G2T, part);       // F partials
  fused_attn<<<dim3(170), 512, 0, stream>>>(part, K16f, Abits, VTf, (float*)d_out);
}

// Round 12
// 176.732 us; speedup vs baseline: 1.0245x; 1.0142x over previous
//
#include <hip/hip_runtime.h>

#define NV 2708
#define INC 1433
#define XCOLS 1472        // padded X/W cols (23*64)
#define UDIM 2752         // padded U dims (43*64)
#define PSTR 2728         // pbuf stride in shorts
#define BSTR 2752
#define SLAB ((size_t)(2752*64))   // fp32 partial slab
#define MWPR 88
#define NSP 4             // proj split-K chunks (K-chunk 384; last 320)
#define NSU 11            // gemmU split-K chunks (2752 = 10*256 + 192)

typedef __attribute__((ext_vector_type(8))) short bf16x8;
typedef __attribute__((ext_vector_type(4))) float f32x4;
typedef __attribute__((ext_vector_type(4))) unsigned short u16x4;

__device__ __forceinline__ unsigned short f2bf(float f){
  union { float f; unsigned int i; } v; v.f = f;
  return (unsigned short)((v.i + 0x7fffu + ((v.i >> 16) & 1u)) >> 16);  // RNE
}

// convert one fp32 row (INC elems, 4B-aligned base) to bf16 with zero pad to
// XCOLS. float2 via parity shift: src+sh is 8B-aligned (sh in {0,1}).
__device__ __forceinline__ void conv_row(const float* __restrict__ src,
                                         unsigned short* __restrict__ dst, int tid){
  const int sh = ((unsigned int)((size_t)src >> 2)) & 1;
  if (tid == 0){ int ce = sh ? 0 : (INC - 1); dst[ce] = f2bf(src[ce]); }
  const float2* s2 = (const float2*)(src + sh);
  for (int c2 = tid; c2 < (INC - 1)/2; c2 += 256){   // 716 pairs
    float2 v = s2[c2];
    int c = sh + c2*2;
    dst[c]     = f2bf(v.x);
    dst[c + 1] = f2bf(v.y);
  }
  for (int c = INC + tid; c < XCOLS; c += 256) dst[c] = 0;
}

// ====== convert_all: X/W/A one-row blocks + U 64x64 tiles (Ubf AND UTbf) ====
__global__ __launch_bounds__(256) void convert_all(
    const float* __restrict__ X, const float* __restrict__ WK,
    const float* __restrict__ WQ, const float* __restrict__ WV,
    const float* __restrict__ U, const int* __restrict__ A,
    unsigned short* __restrict__ Xbf, unsigned short* __restrict__ Wbf,
    unsigned short* __restrict__ Ubf, unsigned short* __restrict__ UTbf,
    unsigned int* __restrict__ Abits)
{
  __shared__ __align__(16) float tpose[64][68];   // 17.4 KB (U-tile branch)
  const int bx = blockIdx.x;
  const int tid = threadIdx.x;
  if (bx < 2752){                      // X row (float2 parity trick)
    const int row = bx;
    unsigned short* dst = Xbf + (size_t)row*XCOLS;
    if (row < NV){
      conv_row(X + (size_t)row*INC, dst, tid);
    } else {
      u16x4 zz = {0,0,0,0};
      for (int c4 = tid; c4 < XCOLS/4; c4 += 256) *(u16x4*)(dst + c4*4) = zz;
    }
  } else if (bx < 2944){               // W row (192 rows)
    const int row = bx - 2752;
    const float* s = (row < 64) ? WK : (row < 128) ? WQ : WV;
    conv_row(s + (size_t)(row & 63)*INC, Wbf + (size_t)row*XCOLS, tid);
  } else if (bx < 5652){               // A row -> bitmask (int4, grouped layout)
    const int i = bx - 2944;
    const int lane = tid & 63, wave = tid >> 6;
    const int* arow = A + (size_t)i*NV;
    unsigned int* drow = Abits + (size_t)i*MWPR;
    for (int g = wave; g < 11; g += 4){
      int base = g*256 + lane*4;
      int4 v = make_int4(0,0,0,0);
      if (base < NV) v = *(const int4*)(arow + base);
      unsigned long long m0 = __ballot(v.x != 0);
      unsigned long long m1 = __ballot(v.y != 0);
      unsigned long long m2 = __ballot(v.z != 0);
      unsigned long long m3 = __ballot(v.w != 0);
      if (lane < 8){
        unsigned long long mm = (lane < 2) ? m0 : (lane < 4) ? m1 : (lane < 6) ? m2 : m3;
        drow[g*8 + lane] = (lane & 1) ? (unsigned int)(mm >> 32) : (unsigned int)mm;
      }
    }
  } else {                             // U 64x64 tile -> Ubf rows + UTbf rows
    const int t = bx - 5652;           // < 1849
    const int tx = t % 43, ty = t / 43;
    const int r0 = ty*64, c0 = tx*64;
    #pragma unroll
    for (int j = 0; j < 4; j++){
      int row = j*16 + (tid >> 4);     // U row within tile
      int c4  = (tid & 15)*4;          // U col within tile
      float4 v = make_float4(0.f,0.f,0.f,0.f);
      if (r0 + row < NV && c0 + c4 < NV)        // NV%4==0: float4 fully valid
        v = *(const float4*)(U + (size_t)(r0+row)*NV + c0 + c4);
      *(float4*)&tpose[row][c4] = v;
      u16x4 h = { f2bf(v.x), f2bf(v.y), f2bf(v.z), f2bf(v.w) };
      *(u16x4*)(Ubf + (size_t)(r0+row)*UDIM + c0 + c4) = h;
    }
    __syncthreads();
    const int i = tid >> 2;            // UT row within tile (UT row c0+i)
    #pragma unroll
    for (int j = 0; j < 4; j++){
      int kk = ((tid & 3) + j*4)*4;    // UT col (k) start
      u16x4 h = { f2bf(tpose[kk+0][i]), f2bf(tpose[kk+1][i]),
                  f2bf(tpose[kk+2][i]), f2bf(tpose[kk+3][i]) };
      *(u16x4*)(UTbf + (size_t)(c0+i)*UDIM + r0 + kk) = h;
    }
  }
}

// ===== proj: partials of {K,Q,V} = Xbf @ Wbf^T. grid (86,4,3). ==============
// 32-row m-tiles, LDS-staged A+B, K-chunk 384. 1032 blocks.
__global__ __launch_bounds__(256) void proj(
    const unsigned short* __restrict__ Xbf, const unsigned short* __restrict__ Wbf,
    float* __restrict__ part)
{
  __shared__ __align__(16) unsigned short At[32*72];
  __shared__ __align__(16) unsigned short Bt[64*72];
  const int tid = threadIdx.x;
  const int lane = tid & 63, wave = tid >> 6, quad = lane >> 4, lr = lane & 15;
  const int m0 = blockIdx.x * 32;
  const int s  = blockIdx.y, z = blockIdx.z;
  const int kbeg = s * 384, kend = min(kbeg + 384, XCOLS);  // last chunk 320
  const int wm = (wave & 1) * 16, wn = (wave >> 1) * 32;
  const unsigned short* Wz = Wbf + (size_t)z*64*XCOLS;
  const int arow = tid >> 3, aseg = tid & 7;
  const int brow = tid >> 2, bseg = tid & 3;
  f32x4 acc[2] = {};

  for (int k0 = kbeg; k0 < kend; k0 += 64){
    *(bf16x8*)&At[arow*72 + aseg*8] =
        *(const bf16x8*)(Xbf + (size_t)(m0+arow)*XCOLS + k0 + aseg*8);
    {
      const unsigned short* b = Wz + (size_t)brow*XCOLS + k0 + bseg*16;
      *(bf16x8*)&Bt[brow*72 + bseg*16]     = *(const bf16x8*)(b);
      *(bf16x8*)&Bt[brow*72 + bseg*16 + 8] = *(const bf16x8*)(b + 8);
    }
    __syncthreads();
    #pragma unroll
    for (int ks = 0; ks < 2; ks++){
      bf16x8 af = *(const bf16x8*)&At[(wm + lr)*72 + ks*32 + quad*8];
      bf16x8 bv[2];
      #pragma unroll
      for (int t = 0; t < 2; t++)
        bv[t] = *(const bf16x8*)&Bt[(wn + t*16 + lr)*72 + ks*32 + quad*8];
      #pragma unroll
      for (int t = 0; t < 2; t++)
        acc[t] = __builtin_amdgcn_mfma_f32_16x16x32_bf16(af, bv[t], acc[t], 0, 0, 0);
    }
    __syncthreads();
  }
  float* dst = part + (size_t)(z*NSP + s) * SLAB;
  #pragma unroll
  for (int t = 0; t < 2; t++)
    #pragma unroll
    for (int e = 0; e < 4; e++)
      dst[(size_t)(m0 + wm + quad*4 + e)*64 + wn + t*16 + lr] = acc[t][e];
}

// K16f frag-linear ; QT16 [c][m] ; VTf frag-linear. grid (688, 3).
__global__ __launch_bounds__(256) void reduce_proj(
    const float* __restrict__ part, unsigned short* __restrict__ K16f,
    unsigned short* __restrict__ QT16, unsigned short* __restrict__ VTf)
{
  int idx = blockIdx.x*256 + threadIdx.x;       // < 2752*64
  int z = blockIdx.y;
  int m = idx >> 6, c = idx & 63;
  const float* base = part + (size_t)z*NSP*SLAB + idx;
  float v = 0.f;
  #pragma unroll
  for (int s = 0; s < NSP; s++) v += base[s*SLAB];
  unsigned short h = (m < NV) ? f2bf(v) : (unsigned short)0;
  if (z == 0){
    if (m < 2720) K16f[((m>>4)*2 + (c>>5))*512 + (m&15)*32 + (c&31)] = h;
  } else if (z == 1){
    QT16[(size_t)c*BSTR + m] = h;
  } else {
    if (m < 2720) VTf[(m>>5)*2048 + c*32 + (m&31)] = h;
  }
}

// ===== gemmU: partials of Arow @ Bcm^T. grid (86, 11). (G = UTbf @ Q) =======
__global__ __launch_bounds__(256) void gemmU(
    const unsigned short* __restrict__ Arow, const unsigned short* __restrict__ Bcm,
    float* __restrict__ part)
{
  __shared__ __align__(16) unsigned short At[32*72];
  __shared__ __align__(16) unsigned short Bt[64*72];
  const int tid = threadIdx.x;
  const int lane = tid & 63, wave = tid >> 6, quad = lane >> 4, lr = lane & 15;
  const int m0 = blockIdx.x * 32;
  const int s  = blockIdx.y;
  const int kbeg = s * 256, kend = min(kbeg + 256, UDIM);   // last chunk 192
  const int wm = (wave & 1) * 16, wn = (wave >> 1) * 32;
  const int arow = tid >> 3, aseg = tid & 7;
  const int bc = tid >> 2, bseg = tid & 3;
  f32x4 acc[2] = {};

  for (int k0 = kbeg; k0 < kend; k0 += 64){
    *(bf16x8*)&At[arow*72 + aseg*8] =
        *(const bf16x8*)(Arow + (size_t)(m0+arow)*UDIM + k0 + aseg*8);
    {
      const unsigned short* b = Bcm + (size_t)bc*BSTR + k0 + bseg*16;
      *(bf16x8*)&Bt[bc*72 + bseg*16]     = *(const bf16x8*)(b);
      *(bf16x8*)&Bt[bc*72 + bseg*16 + 8] = *(const bf16x8*)(b + 8);
    }
    __syncthreads();
    #pragma unroll
    for (int ks = 0; ks < 2; ks++){
      bf16x8 af = *(const bf16x8*)&At[(wm + lr)*72 + ks*32 + quad*8];
      bf16x8 bv[2];
      #pragma unroll
      for (int t = 0; t < 2; t++)
        bv[t] = *(const bf16x8*)&Bt[(wn + t*16 + lr)*72 + ks*32 + quad*8];
      #pragma unroll
      for (int t = 0; t < 2; t++)
        acc[t] = __builtin_amdgcn_mfma_f32_16x16x32_bf16(af, bv[t], acc[t], 0, 0, 0);
    }
    __syncthreads();
  }
  float* dst = part + (size_t)s * SLAB;
  #pragma unroll
  for (int t = 0; t < 2; t++)
    #pragma unroll
    for (int e = 0; e < 4; e++)
      dst[(size_t)(m0 + wm + quad*4 + e)*64 + wn + t*16 + lr] = acc[t][e];
}

// G2T16[c][m] = bf16(G[m][c] * lmbd[m]/64), zero pads. grid 688.
__global__ __launch_bounds__(256) void reduce_g(
    const float* __restrict__ part, const float* __restrict__ lm,
    unsigned short* __restrict__ G2T)
{
  int idx = blockIdx.x*256 + threadIdx.x;
  int m = idx >> 6, c = idx & 63;
  const float* base = part + idx;
  float v = 0.f;
  #pragma unroll
  for (int s = 0; s < NSU; s++) v += base[s*SLAB];
  unsigned short h = 0;
  if (m < NV) h = f2bf(v * lm[m] * (1.0f/64.0f));
  G2T[(size_t)c*BSTR + m] = h;
}

// ====== fused: F = U@G2 (phase 0, folds gemmF) + |F K^T| -> masked exp ======
// + row-sum -> P V.  16 rows/block, 512 threads (8 waves), 170 blocks.
// Phase 0: wave w takes k-steps w, w+8, ... (86 K32 steps); 16x64 fp32
// partials reduced via LDS (aliases pbuf, dead then). Ubf pad rows are 0.
__global__ __launch_bounds__(512) void fused_attn(
    const unsigned short* __restrict__ Ubf, const unsigned short* __restrict__ G2T,
    const unsigned short* __restrict__ K16f,
    const unsigned int* __restrict__ Abits, const unsigned short* __restrict__ VTf,
    float* __restrict__ Hout)
{
  __shared__ __align__(16) unsigned short pbuf[16*PSTR];   // 87.3 KB (phase0: fpart)
  __shared__ __align__(16) unsigned short fbuf[16*64];     // 2 KB
  __shared__ unsigned int mrow[16*MWPR];                   // 5.6 KB
  __shared__ float swave[8][16];
  __shared__ float rinv[16];
  __shared__ __align__(16) float obuf[4][256];             // 4 KB
  const int tid  = threadIdx.x;
  const int lane = tid & 63, wave = tid >> 6;
  const int quad = lane >> 4, lr = lane & 15;
  const int i0 = blockIdx.x * 16;

  // ---- phase 0: F[16][64] = U[i0:i0+16][:] @ G2 ----
  float* fpart = (float*)pbuf;                 // [8][4][256] fp32 = 32 KB
  {
    f32x4 facc[4] = {};
    const unsigned short* ua = Ubf + (size_t)(i0 + lr)*UDIM + quad*8;
    for (int ks = wave; ks < 86; ks += 8){
      const int k0 = ks*32;
      bf16x8 af = *(const bf16x8*)(ua + k0);
      #pragma unroll
      for (int n = 0; n < 4; n++){
        bf16x8 bv = *(const bf16x8*)(G2T + (size_t)(n*16 + lr)*BSTR + k0 + quad*8);
        facc[n] = __builtin_amdgcn_mfma_f32_16x16x32_bf16(af, bv, facc[n], 0, 0, 0);
      }
    }
    #pragma unroll
    for (int n = 0; n < 4; n++)
      *(f32x4*)&fpart[(wave*4 + n)*256 + lane*4] = facc[n];
  }
  for (int idx = tid; idx < 16*MWPR; idx += 512){
    int r = idx / MWPR;
    unsigned int v = 0;
    if (i0 + r < NV) v = Abits[(size_t)(i0 + r)*MWPR + (idx - r*MWPR)];
    mrow[idx] = v;
  }
  __syncthreads();
  // reduce 8 wave-partials -> fbuf bf16 (C layout: row=(l>>4)*4+e, col=n*16+(l&15))
  for (int idx = tid; idx < 1024; idx += 512){
    int n = idx >> 8, l4 = idx & 255;
    float v = 0.f;
    #pragma unroll
    for (int w = 0; w < 8; w++) v += fpart[(w*4 + n)*256 + l4];
    int l = l4 >> 2, e = l4 & 3;
    fbuf[((l >> 4)*4 + e)*64 + n*16 + (l & 15)] = f2bf(v);
  }
  __syncthreads();

  // ---- phase A: S = |F K^T| masked exp, P in pbuf, row-sums ----
  const bf16x8 af0 = *(const bf16x8*)&fbuf[lr*64 + quad*8];
  const bf16x8 af1 = *(const bf16x8*)&fbuf[lr*64 + 32 + quad*8];
  float psum[4] = {0.f, 0.f, 0.f, 0.f};
  {
    int t = wave;
    const unsigned short* kb = K16f + t*1024 + lr*32 + quad*8;
    bf16x8 b0 = *(const bf16x8*)(kb);
    bf16x8 b1 = *(const bf16x8*)(kb + 512);
    while (t < 170){
      int tn = t + 8;
      bf16x8 n0 = b0, n1 = b1;
      if (tn < 170){
        const unsigned short* nb = K16f + tn*1024 + lr*32 + quad*8;
        n0 = *(const bf16x8*)(nb);
        n1 = *(const bf16x8*)(nb + 512);
      }
      f32x4 sv0 = {}, sv1 = {};
      sv0 = __builtin_amdgcn_mfma_f32_16x16x32_bf16(af0, b0, sv0, 0, 0, 0);
      sv1 = __builtin_amdgcn_mfma_f32_16x16x32_bf16(af1, b1, sv1, 0, 0, 0);
      f32x4 sv = sv0 + sv1;
      {
        int col = t*16 + lr;
        int ss = col & 255, ll = ss >> 2;
        int wsh = (col >> 8)*8 + (ss & 3)*2 + (ll >> 5);
        int bit = ll & 31;
        #pragma unroll
        for (int e = 0; e < 4; e++){
          int r = quad*4 + e;
          float p = 0.f;
          if ((mrow[r*MWPR + wsh] >> bit) & 1u) p = __expf(fabsf(sv[e]));
          psum[e] += p;
          pbuf[r*PSTR + col] = f2bf(p);
        }
      }
      b0 = n0; b1 = n1; t = tn;
    }
  }
  #pragma unroll
  for (int e = 0; e < 4; e++){
    float v = psum[e];
    #pragma unroll
    for (int o = 1; o <= 8; o <<= 1) v += __shfl_xor(v, o, 64);
    if (lr == 0) swave[wave][quad*4 + e] = v;
  }
  __syncthreads();
  if (tid < 16){
    float s = 0.f;
    #pragma unroll
    for (int w = 0; w < 8; w++) s += swave[w][tid];
    rinv[tid] = (s > 0.f) ? (1.f/s) : 0.f;
  }
  __syncthreads();

  // ---- phase C: O = P @ V. wave&3 -> col group, wave>>2 -> kt half. ----
  const int c0 = (wave & 3) * 16;
  const int ktbeg = (wave >> 2) ? 43 : 0;
  const int ktend = (wave >> 2) ? 85 : 43;
  f32x4 acc = {};
  {
    bf16x8 bv = *(const bf16x8*)&VTf[ktbeg*2048 + (c0 + lr)*32 + quad*8];
    for (int kt = ktbeg; kt < ktend; kt++){
      bf16x8 bn = bv;
      if (kt + 1 < ktend) bn = *(const bf16x8*)&VTf[(kt+1)*2048 + (c0 + lr)*32 + quad*8];
      bf16x8 af = *(const bf16x8*)&pbuf[lr*PSTR + kt*32 + quad*8];
      acc = __builtin_amdgcn_mfma_f32_16x16x32_bf16(af, bv, acc, 0, 0, 0);
      bv = bn;
    }
  }
  if (wave >= 4) *(f32x4*)&obuf[wave & 3][lane*4] = acc;
  __syncthreads();
  if (wave < 4){
    f32x4 o = *(const f32x4*)&obuf[wave][lane*4];
    acc += o;
    #pragma unroll
    for (int e = 0; e < 4; e++){
      int r = quad*4 + e;
      int i = i0 + r;
      if (i < NV) Hout[(size_t)i*64 + c0 + lr] = acc[e] * rinv[r];
    }
  }
}

extern "C" void kernel_launch(void* const* d_in, const int* in_sizes, int n_in,
                              void* d_out, int out_size, void* d_ws, size_t ws_size,
                              hipStream_t stream){
  (void)in_sizes; (void)n_in; (void)out_size; (void)ws_size;
  const float* X  = (const float*)d_in[0];
  const int*   A  = (const int*)d_in[1];
  const float* U  = (const float*)d_in[2];
  const float* WK = (const float*)d_in[3];
  const float* WQ = (const float*)d_in[4];
  const float* WV = (const float*)d_in[5];
  const float* lm = (const float*)d_in[6];

  char* ws = (char*)d_ws;
  size_t off = 0;
  auto alloc = [&](size_t bytes){ size_t o = off; off = (off + bytes + 255) & ~(size_t)255; return o; };
  float*          part = (float*)(ws + alloc(12*SLAB*4));                      // 8.45 MB (K/Q/V partials; 0-10 reused for G)
  unsigned short* Ubf  = (unsigned short*)(ws + alloc((size_t)UDIM*UDIM*2));   // 15.15 MB
  unsigned short* UTbf = (unsigned short*)(ws + alloc((size_t)UDIM*UDIM*2));   // 15.15 MB
  unsigned short* Xbf  = (unsigned short*)(ws + alloc((size_t)UDIM*XCOLS*2));  // 8.10 MB
  unsigned short* Wbf  = (unsigned short*)(ws + alloc((size_t)192*XCOLS*2));
  unsigned short* K16f = (unsigned short*)(ws + alloc((size_t)170*1024*2));
  unsigned short* QT16 = (unsigned short*)(ws + alloc((size_t)64*BSTR*2));
  unsigned short* G2T  = (unsigned short*)(ws + alloc((size_t)64*BSTR*2));
  unsigned short* VTf  = (unsigned short*)(ws + alloc((size_t)85*2048*2));
  unsigned int*   Abits= (unsigned int*)(ws + alloc((size_t)NV*MWPR*4));
  // total ~52 MB

  convert_all<<<dim3(7501), 256, 0, stream>>>(X, WK, WQ, WV, U, A,
                                              Xbf, Wbf, Ubf, UTbf, Abits);
  proj<<<dim3(86, NSP, 3), 256, 0, stream>>>(Xbf, Wbf, part);
  reduce_proj<<<dim3(688, 3), 256, 0, stream>>>(part, K16f, QT16, VTf);
  gemmU<<<dim3(86, NSU), 256, 0, stream>>>(UTbf, QT16, part);     // G partials
  reduce_g<<<dim3(688), 256, 0, stream>>>(part, lm, G2T);
  fused_attn<<<dim3(170), 512, 0, stream>>>(Ubf, G2T, K16f, Abits, VTf, (float*)d_out);
}

// Round 13
// 173.290 us; speedup vs baseline: 1.0448x; 1.0199x over previous
//
#include <hip/hip_runtime.h>

#define NV 2708
#define INC 1433
#define XCOLS 1472        // padded X/W cols (23*64)
#define UDIM 2752         // padded U dims (43*64)
#define PSTR 2728         // pbuf stride in shorts
#define BSTR 2752
#define SLAB ((size_t)(2752*64))   // fp32 partial slab
#define MWPR 88
#define NSP 4             // proj split-K chunks (K-chunk 384; last 320)
#define NSU 11            // gemmG split-K chunks (2752 = 10*256 + 192)

typedef __attribute__((ext_vector_type(8))) short bf16x8;
typedef __attribute__((ext_vector_type(4))) float f32x4;
typedef __attribute__((ext_vector_type(4))) unsigned short u16x4;

__device__ __forceinline__ unsigned short f2bf(float f){
  union { float f; unsigned int i; } v; v.f = f;
  return (unsigned short)((v.i + 0x7fffu + ((v.i >> 16) & 1u)) >> 16);  // RNE
}

// convert one fp32 row (INC elems, 4B-aligned base) to bf16 with zero pad to
// XCOLS. float2 via parity shift: src+sh is 8B-aligned (sh in {0,1}).
__device__ __forceinline__ void conv_row(const float* __restrict__ src,
                                         unsigned short* __restrict__ dst, int tid){
  const int sh = ((unsigned int)((size_t)src >> 2)) & 1;
  if (tid == 0){ int ce = sh ? 0 : (INC - 1); dst[ce] = f2bf(src[ce]); }
  const float2* s2 = (const float2*)(src + sh);
  for (int c2 = tid; c2 < (INC - 1)/2; c2 += 256){   // 716 pairs
    float2 v = s2[c2];
    int c = sh + c2*2;
    dst[c]     = f2bf(v.x);
    dst[c + 1] = f2bf(v.y);
  }
  for (int c = INC + tid; c < XCOLS; c += 256) dst[c] = 0;
}

// ====== convert_all: X/W/A one-row blocks. (U branch deleted: consumers
// read fp32 U directly with in-register f2bf -> bit-identical values.) ======
__global__ __launch_bounds__(256) void convert_all(
    const float* __restrict__ X, const float* __restrict__ WK,
    const float* __restrict__ WQ, const float* __restrict__ WV,
    const int* __restrict__ A,
    unsigned short* __restrict__ Xbf, unsigned short* __restrict__ Wbf,
    unsigned int* __restrict__ Abits)
{
  const int bx = blockIdx.x;
  const int tid = threadIdx.x;
  if (bx < 2752){                      // X row (float2 parity trick)
    const int row = bx;
    unsigned short* dst = Xbf + (size_t)row*XCOLS;
    if (row < NV){
      conv_row(X + (size_t)row*INC, dst, tid);
    } else {
      u16x4 zz = {0,0,0,0};
      for (int c4 = tid; c4 < XCOLS/4; c4 += 256) *(u16x4*)(dst + c4*4) = zz;
    }
  } else if (bx < 2944){               // W row (192 rows)
    const int row = bx - 2752;
    const float* s = (row < 64) ? WK : (row < 128) ? WQ : WV;
    conv_row(s + (size_t)(row & 63)*INC, Wbf + (size_t)row*XCOLS, tid);
  } else {                             // A row -> bitmask (int4, grouped layout)
    const int i = bx - 2944;
    const int lane = tid & 63, wave = tid >> 6;
    const int* arow = A + (size_t)i*NV;
    unsigned int* drow = Abits + (size_t)i*MWPR;
    for (int g = wave; g < 11; g += 4){
      int base = g*256 + lane*4;
      int4 v = make_int4(0,0,0,0);
      if (base < NV) v = *(const int4*)(arow + base);
      unsigned long long m0 = __ballot(v.x != 0);
      unsigned long long m1 = __ballot(v.y != 0);
      unsigned long long m2 = __ballot(v.z != 0);
      unsigned long long m3 = __ballot(v.w != 0);
      if (lane < 8){
        unsigned long long mm = (lane < 2) ? m0 : (lane < 4) ? m1 : (lane < 6) ? m2 : m3;
        drow[g*8 + lane] = (lane & 1) ? (unsigned int)(mm >> 32) : (unsigned int)mm;
      }
    }
  }
}

// ===== proj: partials of {K,Q,V} = Xbf @ Wbf^T. grid (86,4,3). ==============
// 32-row m-tiles, LDS-staged A+B, K-chunk 384. 1032 blocks.
__global__ __launch_bounds__(256) void proj(
    const unsigned short* __restrict__ Xbf, const unsigned short* __restrict__ Wbf,
    float* __restrict__ part)
{
  __shared__ __align__(16) unsigned short At[32*72];
  __shared__ __align__(16) unsigned short Bt[64*72];
  const int tid = threadIdx.x;
  const int lane = tid & 63, wave = tid >> 6, quad = lane >> 4, lr = lane & 15;
  const int m0 = blockIdx.x * 32;
  const int s  = blockIdx.y, z = blockIdx.z;
  const int kbeg = s * 384, kend = min(kbeg + 384, XCOLS);  // last chunk 320
  const int wm = (wave & 1) * 16, wn = (wave >> 1) * 32;
  const unsigned short* Wz = Wbf + (size_t)z*64*XCOLS;
  const int arow = tid >> 3, aseg = tid & 7;
  const int brow = tid >> 2, bseg = tid & 3;
  f32x4 acc[2] = {};

  for (int k0 = kbeg; k0 < kend; k0 += 64){
    *(bf16x8*)&At[arow*72 + aseg*8] =
        *(const bf16x8*)(Xbf + (size_t)(m0+arow)*XCOLS + k0 + aseg*8);
    {
      const unsigned short* b = Wz + (size_t)brow*XCOLS + k0 + bseg*16;
      *(bf16x8*)&Bt[brow*72 + bseg*16]     = *(const bf16x8*)(b);
      *(bf16x8*)&Bt[brow*72 + bseg*16 + 8] = *(const bf16x8*)(b + 8);
    }
    __syncthreads();
    #pragma unroll
    for (int ks = 0; ks < 2; ks++){
      bf16x8 af = *(const bf16x8*)&At[(wm + lr)*72 + ks*32 + quad*8];
      bf16x8 bv[2];
      #pragma unroll
      for (int t = 0; t < 2; t++)
        bv[t] = *(const bf16x8*)&Bt[(wn + t*16 + lr)*72 + ks*32 + quad*8];
      #pragma unroll
      for (int t = 0; t < 2; t++)
        acc[t] = __builtin_amdgcn_mfma_f32_16x16x32_bf16(af, bv[t], acc[t], 0, 0, 0);
    }
    __syncthreads();
  }
  float* dst = part + (size_t)(z*NSP + s) * SLAB;
  #pragma unroll
  for (int t = 0; t < 2; t++)
    #pragma unroll
    for (int e = 0; e < 4; e++)
      dst[(size_t)(m0 + wm + quad*4 + e)*64 + wn + t*16 + lr] = acc[t][e];
}

// K16f frag-linear ; QT16 [c][m] ; VTf frag-linear. grid (688, 3).
__global__ __launch_bounds__(256) void reduce_proj(
    const float* __restrict__ part, unsigned short* __restrict__ K16f,
    unsigned short* __restrict__ QT16, unsigned short* __restrict__ VTf)
{
  int idx = blockIdx.x*256 + threadIdx.x;       // < 2752*64
  int z = blockIdx.y;
  int m = idx >> 6, c = idx & 63;
  const float* base = part + (size_t)z*NSP*SLAB + idx;
  float v = 0.f;
  #pragma unroll
  for (int s = 0; s < NSP; s++) v += base[s*SLAB];
  unsigned short h = (m < NV) ? f2bf(v) : (unsigned short)0;
  if (z == 0){
    if (m < 2720) K16f[((m>>4)*2 + (c>>5))*512 + (m&15)*32 + (c&31)] = h;
  } else if (z == 1){
    QT16[(size_t)c*BSTR + m] = h;
  } else {
    if (m < 2720) VTf[(m>>5)*2048 + c*32 + (m&31)] = h;
  }
}

// ===== gemmG: partials of G = U^T @ Q. grid (86, 11). ======================
// A staged from fp32 U with in-kernel transpose: thread reads U[k][m..m+3]
// (float4), converts, scatters 4 bf16 into At[m][k]. Values bit-identical to
// the old UTbf path. B = QT16 [c][k]. K-chunk 256.
__global__ __launch_bounds__(256) void gemmG(
    const float* __restrict__ U, const unsigned short* __restrict__ Bcm,
    float* __restrict__ part)
{
  __shared__ __align__(16) unsigned short At[32*72];
  __shared__ __align__(16) unsigned short Bt[64*72];
  const int tid = threadIdx.x;
  const int lane = tid & 63, wave = tid >> 6, quad = lane >> 4, lr = lane & 15;
  const int m0 = blockIdx.x * 32;
  const int s  = blockIdx.y;
  const int kbeg = s * 256, kend = min(kbeg + 256, UDIM);   // last chunk 192
  const int wm = (wave & 1) * 16, wn = (wave >> 1) * 32;
  const int ml = (tid & 7)*4, kr = tid >> 3;    // m-chunk 0..28, k-row 0..31
  const int bc = tid >> 2, bseg = tid & 3;
  const bool mok = (m0 + ml) < NV;              // m-chunks never straddle NV (2708%4==0)
  f32x4 acc[2] = {};

  for (int k0 = kbeg; k0 < kend; k0 += 64){
    #pragma unroll
    for (int e = 0; e < 2; e++){
      int kl = kr + e*32;
      int row = k0 + kl;
      float4 v = make_float4(0.f,0.f,0.f,0.f);
      if (row < NV && mok) v = *(const float4*)(U + (size_t)row*NV + m0 + ml);
      At[(ml+0)*72 + kl] = f2bf(v.x);
      At[(ml+1)*72 + kl] = f2bf(v.y);
      At[(ml+2)*72 + kl] = f2bf(v.z);
      At[(ml+3)*72 + kl] = f2bf(v.w);
    }
    {
      const unsigned short* b = Bcm + (size_t)bc*BSTR + k0 + bseg*16;
      *(bf16x8*)&Bt[bc*72 + bseg*16]     = *(const bf16x8*)(b);
      *(bf16x8*)&Bt[bc*72 + bseg*16 + 8] = *(const bf16x8*)(b + 8);
    }
    __syncthreads();
    #pragma unroll
    for (int ks = 0; ks < 2; ks++){
      bf16x8 af = *(const bf16x8*)&At[(wm + lr)*72 + ks*32 + quad*8];
      bf16x8 bv[2];
      #pragma unroll
      for (int t = 0; t < 2; t++)
        bv[t] = *(const bf16x8*)&Bt[(wn + t*16 + lr)*72 + ks*32 + quad*8];
      #pragma unroll
      for (int t = 0; t < 2; t++)
        acc[t] = __builtin_amdgcn_mfma_f32_16x16x32_bf16(af, bv[t], acc[t], 0, 0, 0);
    }
    __syncthreads();
  }
  float* dst = part + (size_t)s * SLAB;
  #pragma unroll
  for (int t = 0; t < 2; t++)
    #pragma unroll
    for (int e = 0; e < 4; e++)
      dst[(size_t)(m0 + wm + quad*4 + e)*64 + wn + t*16 + lr] = acc[t][e];
}

// G2T16[c][m] = bf16(G[m][c] * lmbd[m]/64), zero pads. grid 688.
__global__ __launch_bounds__(256) void reduce_g(
    const float* __restrict__ part, const float* __restrict__ lm,
    unsigned short* __restrict__ G2T)
{
  int idx = blockIdx.x*256 + threadIdx.x;
  int m = idx >> 6, c = idx & 63;
  const float* base = part + idx;
  float v = 0.f;
  #pragma unroll
  for (int s = 0; s < NSU; s++) v += base[s*SLAB];
  unsigned short h = 0;
  if (m < NV) h = f2bf(v * lm[m] * (1.0f/64.0f));
  G2T[(size_t)c*BSTR + m] = h;
}

// ====== fused: F = U@G2 (phase 0) + |F K^T| -> masked exp + row-sum -> P V ==
// 16 rows/block, 512 threads (8 waves), 170 blocks. Phase 0 reads fp32 U rows
// directly (in-register f2bf; k >= NV garbage annihilated by G2T zero pads;
// boundary k-steps element-masked -> bit-identical to old Ubf path).
__global__ __launch_bounds__(512) void fused_attn(
    const float* __restrict__ U, const unsigned short* __restrict__ G2T,
    const unsigned short* __restrict__ K16f,
    const unsigned int* __restrict__ Abits, const unsigned short* __restrict__ VTf,
    float* __restrict__ Hout)
{
  __shared__ __align__(16) unsigned short pbuf[16*PSTR];   // 87.3 KB (phase0: fpart)
  __shared__ __align__(16) unsigned short fbuf[16*64];     // 2 KB
  __shared__ unsigned int mrow[16*MWPR];                   // 5.6 KB
  __shared__ float swave[8][16];
  __shared__ float rinv[16];
  __shared__ __align__(16) float obuf[4][256];             // 4 KB
  const int tid  = threadIdx.x;
  const int lane = tid & 63, wave = tid >> 6;
  const int quad = lane >> 4, lr = lane & 15;
  const int i0 = blockIdx.x * 16;

  // ---- phase 0: F[16][64] = U[i0:i0+16][:] @ G2 ----
  float* fpart = (float*)pbuf;                 // [8][4][256] fp32 = 32 KB
  {
    f32x4 facc[4] = {};
    const bool rok = (i0 + lr) < NV;
    const float* urow = U + (size_t)(i0 + lr)*NV;
    for (int ks = wave; ks < 86; ks += 8){
      const int k0 = ks*32;
      const int kc = k0 + quad*8;
      bf16x8 af;
      if (!rok){
        #pragma unroll
        for (int j = 0; j < 8; j++) af[j] = 0;
      } else if (kc + 7 < NV){
        float4 a = *(const float4*)(urow + kc);
        float4 b = *(const float4*)(urow + kc + 4);
        af[0] = (short)f2bf(a.x); af[1] = (short)f2bf(a.y);
        af[2] = (short)f2bf(a.z); af[3] = (short)f2bf(a.w);
        af[4] = (short)f2bf(b.x); af[5] = (short)f2bf(b.y);
        af[6] = (short)f2bf(b.z); af[7] = (short)f2bf(b.w);
      } else {
        #pragma unroll
        for (int j = 0; j < 8; j++){
          int col = kc + j;
          af[j] = (col < NV) ? (short)f2bf(urow[col]) : (short)0;
        }
      }
      #pragma unroll
      for (int n = 0; n < 4; n++){
        bf16x8 bv = *(const bf16x8*)(G2T + (size_t)(n*16 + lr)*BSTR + k0 + quad*8);
        facc[n] = __builtin_amdgcn_mfma_f32_16x16x32_bf16(af, bv, facc[n], 0, 0, 0);
      }
    }
    #pragma unroll
    for (int n = 0; n < 4; n++)
      *(f32x4*)&fpart[(wave*4 + n)*256 + lane*4] = facc[n];
  }
  for (int idx = tid; idx < 16*MWPR; idx += 512){
    int r = idx / MWPR;
    unsigned int v = 0;
    if (i0 + r < NV) v = Abits[(size_t)(i0 + r)*MWPR + (idx - r*MWPR)];
    mrow[idx] = v;
  }
  __syncthreads();
  // reduce 8 wave-partials -> fbuf bf16 (C layout: row=(l>>4)*4+e, col=n*16+(l&15))
  for (int idx = tid; idx < 1024; idx += 512){
    int n = idx >> 8, l4 = idx & 255;
    float v = 0.f;
    #pragma unroll
    for (int w = 0; w < 8; w++) v += fpart[(w*4 + n)*256 + l4];
    int l = l4 >> 2, e = l4 & 3;
    fbuf[((l >> 4)*4 + e)*64 + n*16 + (l & 15)] = f2bf(v);
  }
  __syncthreads();

  // ---- phase A: S = |F K^T| masked exp, P in pbuf, row-sums ----
  const bf16x8 af0 = *(const bf16x8*)&fbuf[lr*64 + quad*8];
  const bf16x8 af1 = *(const bf16x8*)&fbuf[lr*64 + 32 + quad*8];
  float psum[4] = {0.f, 0.f, 0.f, 0.f};
  {
    int t = wave;
    const unsigned short* kb = K16f + t*1024 + lr*32 + quad*8;
    bf16x8 b0 = *(const bf16x8*)(kb);
    bf16x8 b1 = *(const bf16x8*)(kb + 512);
    while (t < 170){
      int tn = t + 8;
      bf16x8 n0 = b0, n1 = b1;
      if (tn < 170){
        const unsigned short* nb = K16f + tn*1024 + lr*32 + quad*8;
        n0 = *(const bf16x8*)(nb);
        n1 = *(const bf16x8*)(nb + 512);
      }
      f32x4 sv0 = {}, sv1 = {};
      sv0 = __builtin_amdgcn_mfma_f32_16x16x32_bf16(af0, b0, sv0, 0, 0, 0);
      sv1 = __builtin_amdgcn_mfma_f32_16x16x32_bf16(af1, b1, sv1, 0, 0, 0);
      f32x4 sv = sv0 + sv1;
      {
        int col = t*16 + lr;
        int ss = col & 255, ll = ss >> 2;
        int wsh = (col >> 8)*8 + (ss & 3)*2 + (ll >> 5);
        int bit = ll & 31;
        #pragma unroll
        for (int e = 0; e < 4; e++){
          int r = quad*4 + e;
          float p = 0.f;
          if ((mrow[r*MWPR + wsh] >> bit) & 1u) p = __expf(fabsf(sv[e]));
          psum[e] += p;
          pbuf[r*PSTR + col] = f2bf(p);
        }
      }
      b0 = n0; b1 = n1; t = tn;
    }
  }
  #pragma unroll
  for (int e = 0; e < 4; e++){
    float v = psum[e];
    #pragma unroll
    for (int o = 1; o <= 8; o <<= 1) v += __shfl_xor(v, o, 64);
    if (lr == 0) swave[wave][quad*4 + e] = v;
  }
  __syncthreads();
  if (tid < 16){
    float s = 0.f;
    #pragma unroll
    for (int w = 0; w < 8; w++) s += swave[w][tid];
    rinv[tid] = (s > 0.f) ? (1.f/s) : 0.f;
  }
  __syncthreads();

  // ---- phase C: O = P @ V. wave&3 -> col group, wave>>2 -> kt half. ----
  const int c0 = (wave & 3) * 16;
  const int ktbeg = (wave >> 2) ? 43 : 0;
  const int ktend = (wave >> 2) ? 85 : 43;
  f32x4 acc = {};
  {
    bf16x8 bv = *(const bf16x8*)&VTf[ktbeg*2048 + (c0 + lr)*32 + quad*8];
    for (int kt = ktbeg; kt < ktend; kt++){
      bf16x8 bn = bv;
      if (kt + 1 < ktend) bn = *(const bf16x8*)&VTf[(kt+1)*2048 + (c0 + lr)*32 + quad*8];
      bf16x8 af = *(const bf16x8*)&pbuf[lr*PSTR + kt*32 + quad*8];
      acc = __builtin_amdgcn_mfma_f32_16x16x32_bf16(af, bv, acc, 0, 0, 0);
      bv = bn;
    }
  }
  if (wave >= 4) *(f32x4*)&obuf[wave & 3][lane*4] = acc;
  __syncthreads();
  if (wave < 4){
    f32x4 o = *(const f32x4*)&obuf[wave][lane*4];
    acc += o;
    #pragma unroll
    for (int e = 0; e < 4; e++){
      int r = quad*4 + e;
      int i = i0 + r;
      if (i < NV) Hout[(size_t)i*64 + c0 + lr] = acc[e] * rinv[r];
    }
  }
}

extern "C" void kernel_launch(void* const* d_in, const int* in_sizes, int n_in,
                              void* d_out, int out_size, void* d_ws, size_t ws_size,
                              hipStream_t stream){
  (void)in_sizes; (void)n_in; (void)out_size; (void)ws_size;
  const float* X  = (const float*)d_in[0];
  const int*   A  = (const int*)d_in[1];
  const float* U  = (const float*)d_in[2];
  const float* WK = (const float*)d_in[3];
  const float* WQ = (const float*)d_in[4];
  const float* WV = (const float*)d_in[5];
  const float* lm = (const float*)d_in[6];

  char* ws = (char*)d_ws;
  size_t off = 0;
  auto alloc = [&](size_t bytes){ size_t o = off; off = (off + bytes + 255) & ~(size_t)255; return o; };
  float*          part = (float*)(ws + alloc(12*SLAB*4));                      // 8.45 MB (K/Q/V; 0-10 reused for G)
  unsigned short* Xbf  = (unsigned short*)(ws + alloc((size_t)UDIM*XCOLS*2));  // 8.10 MB
  unsigned short* Wbf  = (unsigned short*)(ws + alloc((size_t)192*XCOLS*2));
  unsigned short* K16f = (unsigned short*)(ws + alloc((size_t)170*1024*2));
  unsigned short* QT16 = (unsigned short*)(ws + alloc((size_t)64*BSTR*2));
  unsigned short* G2T  = (unsigned short*)(ws + alloc((size_t)64*BSTR*2));
  unsigned short* VTf  = (unsigned short*)(ws + alloc((size_t)85*2048*2));
  unsigned int*   Abits= (unsigned int*)(ws + alloc((size_t)NV*MWPR*4));
  // total ~21 MB

  convert_all<<<dim3(5652), 256, 0, stream>>>(X, WK, WQ, WV, A, Xbf, Wbf, Abits);
  proj<<<dim3(86, NSP, 3), 256, 0, stream>>>(Xbf, Wbf, part);
  reduce_proj<<<dim3(688, 3), 256, 0, stream>>>(part, K16f, QT16, VTf);
  gemmG<<<dim3(86, NSU), 256, 0, stream>>>(U, QT16, part);        // G partials
  reduce_g<<<dim3(688), 256, 0, stream>>>(part, lm, G2T);
  fused_attn<<<dim3(170), 512, 0, stream>>>(U, G2T, K16f, Abits, VTf, (float*)d_out);
}